// Round 1
// baseline (515.731 us; speedup 1.0000x reference)
//
#include <hip/hip_runtime.h>
#include <hip/hip_bf16.h>
#include <stdint.h>

typedef __bf16 bf16_t;
typedef __bf16 bf16x8 __attribute__((ext_vector_type(8)));
typedef __bf16 bf16x4 __attribute__((ext_vector_type(4)));
typedef float f32x4 __attribute__((ext_vector_type(4)));

// Problem constants
#define HIDN 1024
#define NHEAD 8
#define HDIM 128
#define NBATCH 8
#define LQLEN 4096
#define LKLEN 128

__device__ __forceinline__ void gload_lds16(const void* g, void* l) {
  __builtin_amdgcn_global_load_lds(
      (const __attribute__((address_space(1))) unsigned int*)g,
      (__attribute__((address_space(3))) unsigned int*)l, 16, 0, 0);
}

// ---------------------------------------------------------------------------
// f32 -> bf16 convert (vectorized float4 -> bf16x4)
// ---------------------------------------------------------------------------
__global__ __launch_bounds__(256) void convk(const float* __restrict__ in,
                                             bf16_t* __restrict__ out, int n4) {
  int i = blockIdx.x * blockDim.x + threadIdx.x;
  const int stride = gridDim.x * blockDim.x;
  for (; i < n4; i += stride) {
    const float4 v = ((const float4*)in)[i];
    bf16x4 o;
    o[0] = (bf16_t)v.x; o[1] = (bf16_t)v.y; o[2] = (bf16_t)v.z; o[3] = (bf16_t)v.w;
    ((bf16x4*)out)[i] = o;
  }
}

// ---------------------------------------------------------------------------
// C = A[M,1024] @ B[1024,1024]^T (+bias), A/B bf16 row-major (B in weight layout)
// m97-structure: 128x128 tile, BK=32, 4 waves (2x2), global_load_lds width 16.
// MODE 0: bf16 head-layout store  [B, H, LROW, 128]   (Qh / Ah / Kh)
// MODE 1: bf16 transposed head    [B, H, 128, LROW]   (Vt; LROW==128)
// MODE 2: f32 plain row-major + bias                  (final out)
// ---------------------------------------------------------------------------
template <int MODE, int LROW>
__global__ __launch_bounds__(256) void gemm_bt(const bf16_t* __restrict__ A,
                                               const bf16_t* __restrict__ Bw,
                                               const float* __restrict__ bias,
                                               void* __restrict__ Cout) {
  constexpr int BK = 32;
  __shared__ uint4 AsRaw[128 * BK * 2 / 16];
  __shared__ uint4 BsRaw[128 * BK * 2 / 16];
  bf16_t* As = (bf16_t*)AsRaw;
  bf16_t* Bs = (bf16_t*)BsRaw;

  const int tid = threadIdx.x;
  const int wid = tid >> 6;
  const int lane = tid & 63;
  const int lr = lane & 15, lh = lane >> 4;
  const int m0 = blockIdx.x * 128, n0 = blockIdx.y * 128;
  const int wm = (wid >> 1) * 64, wn = (wid & 1) * 64;

  f32x4 acc[4][4] = {};

  const int srow = lane >> 2;          // row within 16-row chunk
  const int scol = (lane & 3) * 16;    // byte offset within 64B row

  for (int k0 = 0; k0 < HIDN; k0 += BK) {
#pragma unroll
    for (int i = 0; i < 2; ++i) {
      const int c = wid + i * 4;  // chunk 0..7, 16 rows each
      const int row = c * 16 + srow;
      gload_lds16((const char*)A + ((size_t)(m0 + row) * HIDN + k0) * 2 + scol,
                  (char*)As + c * 1024);
      gload_lds16((const char*)Bw + ((size_t)(n0 + row) * HIDN + k0) * 2 + scol,
                  (char*)Bs + c * 1024);
    }
    __syncthreads();

    bf16x8 af[4], bfr[4];
#pragma unroll
    for (int i = 0; i < 4; ++i) {
      af[i]  = *(const bf16x8*)(As + (wm + i * 16 + lr) * BK + lh * 8);
      bfr[i] = *(const bf16x8*)(Bs + (wn + i * 16 + lr) * BK + lh * 8);
    }
#pragma unroll
    for (int i = 0; i < 4; ++i)
#pragma unroll
      for (int j = 0; j < 4; ++j)
        acc[i][j] = __builtin_amdgcn_mfma_f32_16x16x32_bf16(af[i], bfr[j], acc[i][j], 0, 0, 0);
    __syncthreads();
  }

  // Epilogue. C/D layout: col = lane&15, row = (lane>>4)*4 + reg.
#pragma unroll
  for (int i = 0; i < 4; ++i) {
#pragma unroll
    for (int r = 0; r < 4; ++r) {
      const int gm = m0 + wm + i * 16 + lh * 4 + r;
#pragma unroll
      for (int j = 0; j < 4; ++j) {
        const int gn = n0 + wn + j * 16 + lr;
        const float v = acc[i][j][r] + bias[gn];
        if constexpr (MODE == 2) {
          ((float*)Cout)[(size_t)gm * HIDN + gn] = v;
        } else {
          const int b = gm / LROW, l = gm - b * LROW;
          const int h = gn >> 7, d = gn & 127;
          size_t idx;
          if constexpr (MODE == 0)
            idx = (((size_t)(b * NHEAD + h) * LROW + l) << 7) + d;
          else
            idx = (((size_t)(b * NHEAD + h) * 128 + d) << 7) + l;
          ((bf16_t*)Cout)[idx] = (bf16_t)v;
        }
      }
    }
  }
}

// ---------------------------------------------------------------------------
// Fused attention: energy = QK^T/sqrt(128) + Ah, mask, softmax, x = P V
// Grid: (LQ/64, B*H). 4 waves, 16 q-rows per wave. K/V in swizzled LDS.
// Writes X[b, q, h*128+d] bf16 (layout ready for the FC GEMM).
// ---------------------------------------------------------------------------
__global__ __launch_bounds__(256) void attn_kernel(
    const bf16_t* __restrict__ Qh, const bf16_t* __restrict__ Ah,
    const bf16_t* __restrict__ Kh, const bf16_t* __restrict__ Vt,
    const int* __restrict__ mask, bf16_t* __restrict__ X) {
  __shared__ uint4 KsRaw[2048];  // 32KB: K head [k][d], XOR-swizzled
  __shared__ uint4 VsRaw[2048];  // 32KB: V^T head [d][k], XOR-swizzled
  __shared__ float Ms[128];
  char* Ks = (char*)KsRaw;
  char* Vs = (char*)VsRaw;

  const int tid = threadIdx.x, wid = tid >> 6, lane = tid & 63;
  const int lr = lane & 15, lh = lane >> 4;
  const int bh = blockIdx.y, b = bh >> 3, h = bh & 7;
  const int q0 = blockIdx.x * 64;

  // Stage K and V^T (32KB each) with st-swizzle: byte ^= (row&7)<<4
  {
    const char* Kg = (const char*)(Kh + (size_t)bh * 16384);
    const char* Vg = (const char*)(Vt + (size_t)bh * 16384);
#pragma unroll
    for (int it = 0; it < 8; ++it) {
      const int e = it * 256 + tid;     // 16B-chunk index, 2048 total
      const int row = e >> 4;
      const int cb = (e & 15) << 4;
      const int dst = row * 256 + (cb ^ ((row & 7) << 4));
      *(uint4*)(Ks + dst) = *(const uint4*)(Kg + row * 256 + cb);
      *(uint4*)(Vs + dst) = *(const uint4*)(Vg + row * 256 + cb);
    }
  }
  if (tid < 128) Ms[tid] = (mask[b * 128 + tid] == 0) ? 0.f : 1.f;

  // Q fragments, held in registers for the whole block
  bf16x8 qf[4];
  {
    const bf16_t* Qb = Qh + ((size_t)bh * LQLEN + q0 + wid * 16 + lr) * 128;
#pragma unroll
    for (int s = 0; s < 4; ++s) qf[s] = *(const bf16x8*)(Qb + s * 32 + lh * 8);
  }
  __syncthreads();

  // energy tiles: acc[nt] covers k-cols nt*16..+16 for this wave's 16 q-rows
  f32x4 acc[8] = {};
#pragma unroll
  for (int nt = 0; nt < 8; ++nt) {
#pragma unroll
    for (int s = 0; s < 4; ++s) {
      const int row = nt * 16 + lr;
      const int cb = (s * 64 + lh * 16) ^ ((row & 7) << 4);
      const bf16x8 kf = *(const bf16x8*)(Ks + row * 256 + cb);
      acc[nt] = __builtin_amdgcn_mfma_f32_16x16x32_bf16(qf[s], kf, acc[nt], 0, 0, 0);
    }
  }

  // bias + mask + wave-parallel softmax (row r lives on the 16-lane group lh)
  float ex[8][4];
  float rsum[4];
  const float sc = 0.08838834764831845f;  // 1/sqrt(128)
  const bf16_t* Ab = Ah + ((size_t)bh * LQLEN + q0 + wid * 16) * 128;
#pragma unroll
  for (int r = 0; r < 4; ++r) {
    const int row = lh * 4 + r;
    float mx = -3.0e38f;
#pragma unroll
    for (int nt = 0; nt < 8; ++nt) {
      const int col = nt * 16 + lr;
      float e = acc[nt][r] * sc + (float)Ab[row * 128 + col];
      e = (Ms[col] != 0.f) ? e : -1.0e10f;
      ex[nt][r] = e;
      mx = fmaxf(mx, e);
    }
    mx = fmaxf(mx, __shfl_xor(mx, 1));
    mx = fmaxf(mx, __shfl_xor(mx, 2));
    mx = fmaxf(mx, __shfl_xor(mx, 4));
    mx = fmaxf(mx, __shfl_xor(mx, 8));
    float s_ = 0.f;
#pragma unroll
    for (int nt = 0; nt < 8; ++nt) {
      const float p = expf(ex[nt][r] - mx);
      ex[nt][r] = p;
      s_ += p;
    }
    s_ += __shfl_xor(s_, 1);
    s_ += __shfl_xor(s_, 2);
    s_ += __shfl_xor(s_, 4);
    s_ += __shfl_xor(s_, 8);
    rsum[r] = s_;
  }

  __syncthreads();  // everyone done reading Ks -> reuse it for P
  char* Pb = Ks + wid * 4096;  // per-wave 16x128 bf16, swizzled
#pragma unroll
  for (int r = 0; r < 4; ++r) {
    const int row = lh * 4 + r;
#pragma unroll
    for (int nt = 0; nt < 8; ++nt) {
      const int col = nt * 16 + lr;
      const int off = (row * 256 + col * 2) ^ ((row & 7) << 4);
      *(bf16_t*)(Pb + off) = (bf16_t)ex[nt][r];
    }
  }
  __syncthreads();

  // x = P V : A = P (row = lane&15, k contiguous), B from Vt [d][k]
  bf16x8 pf[4];
#pragma unroll
  for (int s = 0; s < 4; ++s)
    pf[s] = *(const bf16x8*)(Pb + lr * 256 + ((s * 64 + lh * 16) ^ ((lr & 7) << 4)));
  f32x4 acc2[8] = {};
#pragma unroll
  for (int nt = 0; nt < 8; ++nt) {
#pragma unroll
    for (int s = 0; s < 4; ++s) {
      const int row = nt * 16 + lr;
      const int cb = (s * 64 + lh * 16) ^ ((row & 7) << 4);
      const bf16x8 vf = *(const bf16x8*)(Vs + row * 256 + cb);
      acc2[nt] = __builtin_amdgcn_mfma_f32_16x16x32_bf16(pf[s], vf, acc2[nt], 0, 0, 0);
    }
  }

  // epilogue: normalize by row-sum, store bf16 in [B, LQ, H*128] layout
  float rs[4];
#pragma unroll
  for (int r = 0; r < 4; ++r) rs[r] = 1.f / rsum[r];
  bf16_t* Xb = X + ((size_t)b * LQLEN + q0 + wid * 16) * HIDN + h * 128;
#pragma unroll
  for (int nt = 0; nt < 8; ++nt)
#pragma unroll
    for (int r = 0; r < 4; ++r)
      Xb[(size_t)(lh * 4 + r) * HIDN + nt * 16 + lr] = (bf16_t)(acc2[nt][r] * rs[r]);
}

// ---------------------------------------------------------------------------
extern "C" void kernel_launch(void* const* d_in, const int* in_sizes, int n_in,
                              void* d_out, int out_size, void* d_ws, size_t ws_size,
                              hipStream_t stream) {
  const float* query = (const float*)d_in[0];
  const float* key   = (const float*)d_in[1];
  const float* value = (const float*)d_in[2];
  const float* atten = (const float*)d_in[3];
  const int*   mask  = (const int*)d_in[4];
  const float* Wq  = (const float*)d_in[5];  const float* bq   = (const float*)d_in[6];
  const float* Wk  = (const float*)d_in[7];  const float* bk   = (const float*)d_in[8];
  const float* Wv  = (const float*)d_in[9];  const float* bv   = (const float*)d_in[10];
  const float* Wat = (const float*)d_in[11]; const float* batt = (const float*)d_in[12];
  const float* Wfc = (const float*)d_in[13]; const float* bfc  = (const float*)d_in[14];

  char* ws = (char*)d_ws;
  bf16_t* qbf = (bf16_t*)(ws + 0x0000000);   // 64MB  [B,LQ,HID] bf16
  bf16_t* abf = (bf16_t*)(ws + 0x4000000);   // 64MB
  bf16_t* Qh  = (bf16_t*)(ws + 0x8000000);   // 64MB  [B,H,LQ,HD]
  bf16_t* Ah  = (bf16_t*)(ws + 0xC000000);   // 64MB
  char* sm = ws + 0x10000000;
  bf16_t* kbf = (bf16_t*)(sm + 0x000000);
  bf16_t* vbf = (bf16_t*)(sm + 0x200000);
  bf16_t* wqb = (bf16_t*)(sm + 0x400000);
  bf16_t* wkb = (bf16_t*)(sm + 0x600000);
  bf16_t* wvb = (bf16_t*)(sm + 0x800000);
  bf16_t* wab = (bf16_t*)(sm + 0xA00000);
  bf16_t* wfb = (bf16_t*)(sm + 0xC00000);
  bf16_t* Kh  = (bf16_t*)(sm + 0xE00000);    // [B,H,LK,HD]
  bf16_t* Vt  = (bf16_t*)(sm + 0x1000000);   // [B,H,HD,LK]
  bf16_t* X   = qbf;  // attention output reuses qbf (dead after Q-proj)

  auto conv = [&](const float* src, bf16_t* dst, int n) {
    const int n4 = n >> 2;
    int g = (n4 + 255) >> 8; if (g > 2048) g = 2048;
    convk<<<dim3(g), dim3(256), 0, stream>>>(src, dst, n4);
  };
  conv(query, qbf, NBATCH * LQLEN * HIDN);
  conv(atten, abf, NBATCH * LQLEN * HIDN);
  conv(key,   kbf, NBATCH * LKLEN * HIDN);
  conv(value, vbf, NBATCH * LKLEN * HIDN);
  conv(Wq,  wqb, HIDN * HIDN);
  conv(Wk,  wkb, HIDN * HIDN);
  conv(Wv,  wvb, HIDN * HIDN);
  conv(Wat, wab, HIDN * HIDN);
  conv(Wfc, wfb, HIDN * HIDN);

  // K/V projections (M = B*LK = 1024)
  gemm_bt<0, 128><<<dim3(8, 8), dim3(256), 0, stream>>>(kbf, wkb, bk, (void*)Kh);
  gemm_bt<1, 128><<<dim3(8, 8), dim3(256), 0, stream>>>(vbf, wvb, bv, (void*)Vt);

  // Q / atten projections (M = B*LQ = 32768)
  gemm_bt<0, LQLEN><<<dim3(256, 8), dim3(256), 0, stream>>>(qbf, wqb, bq, (void*)Qh);
  gemm_bt<0, LQLEN><<<dim3(256, 8), dim3(256), 0, stream>>>(abf, wab, batt, (void*)Ah);

  // fused attention
  attn_kernel<<<dim3(LQLEN / 64, NBATCH * NHEAD), dim3(256), 0, stream>>>(
      Qh, Ah, Kh, Vt, mask, X);

  // final FC -> f32 out
  gemm_bt<2, LQLEN><<<dim3(256, 8), dim3(256), 0, stream>>>(X, wfb, bfc, d_out);
}

// Round 2
// 477.538 us; speedup vs baseline: 1.0800x; 1.0800x over previous
//
#include <hip/hip_runtime.h>
#include <hip/hip_bf16.h>
#include <stdint.h>

typedef __bf16 bf16_t;
typedef __bf16 bf16x8 __attribute__((ext_vector_type(8)));
typedef __bf16 bf16x4 __attribute__((ext_vector_type(4)));
typedef float f32x4 __attribute__((ext_vector_type(4)));

// Problem constants
#define HIDN 1024
#define NHEAD 8
#define HDIM 128
#define NBATCH 8
#define LQLEN 4096
#define LKLEN 128

__device__ __forceinline__ void gload_lds16(const void* g, void* l) {
  __builtin_amdgcn_global_load_lds(
      (const __attribute__((address_space(1))) unsigned int*)g,
      (__attribute__((address_space(3))) unsigned int*)l, 16, 0, 0);
}

// ---------------------------------------------------------------------------
// f32 -> bf16 convert (vectorized float4 -> bf16x4)
// ---------------------------------------------------------------------------
__global__ __launch_bounds__(256) void convk(const float* __restrict__ in,
                                             bf16_t* __restrict__ out, int n4) {
  int i = blockIdx.x * blockDim.x + threadIdx.x;
  const int stride = gridDim.x * blockDim.x;
  for (; i < n4; i += stride) {
    const float4 v = ((const float4*)in)[i];
    bf16x4 o;
    o[0] = (bf16_t)v.x; o[1] = (bf16_t)v.y; o[2] = (bf16_t)v.z; o[3] = (bf16_t)v.w;
    ((bf16x4*)out)[i] = o;
  }
}

// ---------------------------------------------------------------------------
// Phased big GEMM: C[32768,1024] = A[32768,1024] @ Bw[1024,1024]^T + bias
// BM=128, BN=256, BK=64. 512 threads = 8 waves (2 x 4). Per-wave out 64x64.
// LDS: 3-slot ring, 48KB/slot (A 16KB + B 32KB) = 144KB.
//   Ring-of-3 makes prefetch WAR-safe by construction: during tile t we stage
//   tile t+2 into slot (t+2)%3 == (t-1)%3, whose reads finished before tile t.
// T2: st_16x32 swizzle (flip byte bit5 by row bit2): linear LDS dest,
//   inverse-swizzled GLOBAL source, swizzled ds_read.
// T4: vmcnt(6) at tile boundaries (6 loads/wave/tile in flight), vmcnt(0)
//   only at the last boundary.  T5: setprio around MFMA clusters.
// MODE 0: bf16 head-layout store [B, H, 4096, 128];  MODE 2: f32 row-major.
// ---------------------------------------------------------------------------
template <int MODE>
__global__ __launch_bounds__(512, 2) void gemm8p(const bf16_t* __restrict__ A,
                                                 const bf16_t* __restrict__ Bw,
                                                 const float* __restrict__ bias,
                                                 void* __restrict__ Cout) {
  constexpr int NT = 16;       // K / 64
  constexpr int SLOT = 49152;  // 48KB
  __shared__ uint4 smem_raw[9216];  // 144KB
  char* smem = (char*)smem_raw;

  const int tid = threadIdx.x;
  const int wid = tid >> 6, lane = tid & 63;
  const int lr = lane & 15, lh = lane >> 4;
  const int wr = wid >> 2, wc = wid & 3;  // wave grid 2 (M) x 4 (N)

  // XCD-aware swizzle (1024 blocks, 1024 % 8 == 0 -> bijective)
  const int bid = blockIdx.x;
  const int wg = (bid & 7) * 128 + (bid >> 3);
  const int m_blk = wg & 255, n_blk = wg >> 8;
  const int m0 = m_blk * 128, n0 = n_blk * 256;

  // ---- staging map: thread tid covers 16B chunk c = tid + i*512 (linear LDS)
  // global source is inverse-swizzled: row = tid>>3 (+64*i), colb pre-XORed.
  const int srow = tid >> 3;
  const int scolb = ((tid & 7) << 4) ^ (((tid >> 5) & 1) << 5);
  const char* gA0 = (const char*)A + (size_t)(m0 + srow) * 2048 + scolb;
  const char* gA1 = gA0 + (size_t)64 * 2048;
  const char* gB0 = (const char*)Bw + (size_t)(n0 + srow) * 2048 + scolb;
  const char* gB1 = gB0 + (size_t)64 * 2048;
  const char* gB2 = gB0 + (size_t)128 * 2048;
  const char* gB3 = gB0 + (size_t)192 * 2048;
  const int dA0 = tid * 16, dA1 = 8192 + tid * 16;
  const int dB0 = 16384 + tid * 16, dB1 = 24576 + tid * 16;
  const int dB2 = 32768 + tid * 16, dB3 = 40960 + tid * 16;

  // ---- read-side constants (swizzle: bit5 ^= row bit2 = lr bit2)
  const int colsw = (lh << 4) ^ ((lane & 4) << 3);
  const int arow0 = wr * 64 + lr;
  const int brow0 = wc * 64 + lr;

  f32x4 acc[4][4] = {};

  // ---- prologue: stage tiles 0,1; wait until tile 0 landed (6 outstanding)
#pragma unroll
  for (int tt = 0; tt < 2; ++tt) {
    char* dst = smem + tt * SLOT;
    const int kb = tt * 128;
    gload_lds16(gA0 + kb, dst + dA0);
    gload_lds16(gA1 + kb, dst + dA1);
    gload_lds16(gB0 + kb, dst + dB0);
    gload_lds16(gB1 + kb, dst + dB1);
    gload_lds16(gB2 + kb, dst + dB2);
    gload_lds16(gB3 + kb, dst + dB3);
  }
  asm volatile("s_waitcnt vmcnt(6)" ::: "memory");
  __builtin_amdgcn_s_barrier();

  for (int t = 0; t < NT; ++t) {
    const char* sA = smem + (t % 3) * SLOT;
    const char* sB = sA + 16384;
    char* dst = smem + ((t + 2) % 3) * SLOT;
    const int kb = (t + 2) * 128;
    const bool pf = (t < NT - 2);

    // ===== phase 0: issue B(all) + A(f0,f1) reads, 3 stage loads ===========
    bf16x8 bfrag[4][2], af[2][2];
#pragma unroll
    for (int j = 0; j < 4; ++j)
#pragma unroll
      for (int kk = 0; kk < 2; ++kk)
        bfrag[j][kk] = *(const bf16x8*)(sB + (brow0 + j * 16) * 128 + kk * 64 + colsw);
#pragma unroll
    for (int f = 0; f < 2; ++f)
#pragma unroll
      for (int kk = 0; kk < 2; ++kk)
        af[f][kk] = *(const bf16x8*)(sA + (arow0 + f * 16) * 128 + kk * 64 + colsw);
    if (pf) {
      gload_lds16(gA0 + kb, dst + dA0);
      gload_lds16(gA1 + kb, dst + dA1);
      gload_lds16(gB0 + kb, dst + dB0);
    }
    __builtin_amdgcn_s_barrier();
    asm volatile("s_waitcnt lgkmcnt(0)" ::: "memory");
    __builtin_amdgcn_s_setprio(1);
#pragma unroll
    for (int f = 0; f < 2; ++f)
#pragma unroll
      for (int j = 0; j < 4; ++j)
#pragma unroll
        for (int kk = 0; kk < 2; ++kk)
          acc[f][j] = __builtin_amdgcn_mfma_f32_16x16x32_bf16(af[f][kk], bfrag[j][kk], acc[f][j], 0, 0, 0);
    __builtin_amdgcn_s_setprio(0);
    __builtin_amdgcn_s_barrier();

    // ===== phase 1: issue A(f2,f3) reads, 3 stage loads ====================
#pragma unroll
    for (int f = 0; f < 2; ++f)
#pragma unroll
      for (int kk = 0; kk < 2; ++kk)
        af[f][kk] = *(const bf16x8*)(sA + (arow0 + (f + 2) * 16) * 128 + kk * 64 + colsw);
    if (pf) {
      gload_lds16(gB1 + kb, dst + dB1);
      gload_lds16(gB2 + kb, dst + dB2);
      gload_lds16(gB3 + kb, dst + dB3);
    }
    __builtin_amdgcn_s_barrier();
    asm volatile("s_waitcnt lgkmcnt(0)" ::: "memory");
    __builtin_amdgcn_s_setprio(1);
#pragma unroll
    for (int f = 0; f < 2; ++f)
#pragma unroll
      for (int j = 0; j < 4; ++j)
#pragma unroll
        for (int kk = 0; kk < 2; ++kk)
          acc[f + 2][j] = __builtin_amdgcn_mfma_f32_16x16x32_bf16(af[f][kk], bfrag[j][kk], acc[f + 2][j], 0, 0, 0);
    __builtin_amdgcn_s_setprio(0);

    // ===== tile boundary: counted vmcnt, full drain only at the end ========
    if (t < NT - 1) {
      __builtin_amdgcn_sched_barrier(0);
      if (t == NT - 2)
        asm volatile("s_waitcnt vmcnt(0) lgkmcnt(0)" ::: "memory");
      else
        asm volatile("s_waitcnt vmcnt(6) lgkmcnt(0)" ::: "memory");
      __builtin_amdgcn_s_barrier();
    }
  }

  // ---- epilogue. C/D layout: col = lane&15, row = (lane>>4)*4 + reg.
  if constexpr (MODE == 2) {
    float* C = (float*)Cout;
#pragma unroll
    for (int f = 0; f < 4; ++f) {
      const int gm = m0 + wr * 64 + f * 16 + lh * 4;
#pragma unroll
      for (int j = 0; j < 4; ++j) {
        const int gn = n0 + wc * 64 + j * 16 + lr;
        const float bb = bias[gn];
#pragma unroll
        for (int r = 0; r < 4; ++r)
          C[(size_t)(gm + r) * HIDN + gn] = acc[f][j][r] + bb;
      }
    }
  } else {
    bf16_t* C = (bf16_t*)Cout;
#pragma unroll
    for (int f = 0; f < 4; ++f) {
      const int gm = m0 + wr * 64 + f * 16 + lh * 4;
#pragma unroll
      for (int j = 0; j < 4; ++j) {
        const int gn = n0 + wc * 64 + j * 16 + lr;
        const float bb = bias[gn];
        const int h = gn >> 7, d = gn & 127;
#pragma unroll
        for (int r = 0; r < 4; ++r) {
          const int b = (gm + r) >> 12, l = (gm + r) & 4095;
          C[(((size_t)(b * NHEAD + h) * LQLEN + l) << 7) + d] = (bf16_t)(acc[f][j][r] + bb);
        }
      }
    }
  }
}

// ---------------------------------------------------------------------------
// Small GEMM (m97 structure) for the K/V projections (M = 1024 only)
// MODE 0: bf16 head-layout store  [B, H, LROW, 128]   (Kh)
// MODE 1: bf16 transposed head    [B, H, 128, LROW]   (Vt; LROW==128)
// ---------------------------------------------------------------------------
template <int MODE, int LROW>
__global__ __launch_bounds__(256) void gemm_bt(const bf16_t* __restrict__ A,
                                               const bf16_t* __restrict__ Bw,
                                               const float* __restrict__ bias,
                                               void* __restrict__ Cout) {
  constexpr int BK = 32;
  __shared__ uint4 AsRaw[128 * BK * 2 / 16];
  __shared__ uint4 BsRaw[128 * BK * 2 / 16];
  bf16_t* As = (bf16_t*)AsRaw;
  bf16_t* Bs = (bf16_t*)BsRaw;

  const int tid = threadIdx.x;
  const int wid = tid >> 6;
  const int lane = tid & 63;
  const int lr = lane & 15, lh = lane >> 4;
  const int m0 = blockIdx.x * 128, n0 = blockIdx.y * 128;
  const int wm = (wid >> 1) * 64, wn = (wid & 1) * 64;

  f32x4 acc[4][4] = {};

  const int srow = lane >> 2;
  const int scol = (lane & 3) * 16;

  for (int k0 = 0; k0 < HIDN; k0 += BK) {
#pragma unroll
    for (int i = 0; i < 2; ++i) {
      const int c = wid + i * 4;
      const int row = c * 16 + srow;
      gload_lds16((const char*)A + ((size_t)(m0 + row) * HIDN + k0) * 2 + scol,
                  (char*)As + c * 1024);
      gload_lds16((const char*)Bw + ((size_t)(n0 + row) * HIDN + k0) * 2 + scol,
                  (char*)Bs + c * 1024);
    }
    __syncthreads();

    bf16x8 af[4], bfr[4];
#pragma unroll
    for (int i = 0; i < 4; ++i) {
      af[i]  = *(const bf16x8*)(As + (wm + i * 16 + lr) * BK + lh * 8);
      bfr[i] = *(const bf16x8*)(Bs + (wn + i * 16 + lr) * BK + lh * 8);
    }
#pragma unroll
    for (int i = 0; i < 4; ++i)
#pragma unroll
      for (int j = 0; j < 4; ++j)
        acc[i][j] = __builtin_amdgcn_mfma_f32_16x16x32_bf16(af[i], bfr[j], acc[i][j], 0, 0, 0);
    __syncthreads();
  }

#pragma unroll
  for (int i = 0; i < 4; ++i) {
#pragma unroll
    for (int r = 0; r < 4; ++r) {
      const int gm = m0 + wm + i * 16 + lh * 4 + r;
#pragma unroll
      for (int j = 0; j < 4; ++j) {
        const int gn = n0 + wn + j * 16 + lr;
        const float v = acc[i][j][r] + bias[gn];
        const int b = gm / LROW, l = gm - b * LROW;
        const int h = gn >> 7, d = gn & 127;
        size_t idx;
        if constexpr (MODE == 0)
          idx = (((size_t)(b * NHEAD + h) * LROW + l) << 7) + d;
        else
          idx = (((size_t)(b * NHEAD + h) * 128 + d) << 7) + l;
        ((bf16_t*)Cout)[idx] = (bf16_t)v;
      }
    }
  }
}

// ---------------------------------------------------------------------------
// Fused attention: energy = QK^T/sqrt(128) + Ah, mask, softmax, x = P V
// ---------------------------------------------------------------------------
__global__ __launch_bounds__(256) void attn_kernel(
    const bf16_t* __restrict__ Qh, const bf16_t* __restrict__ Ah,
    const bf16_t* __restrict__ Kh, const bf16_t* __restrict__ Vt,
    const int* __restrict__ mask, bf16_t* __restrict__ X) {
  __shared__ uint4 KsRaw[2048];
  __shared__ uint4 VsRaw[2048];
  __shared__ float Ms[128];
  char* Ks = (char*)KsRaw;
  char* Vs = (char*)VsRaw;

  const int tid = threadIdx.x, wid = tid >> 6, lane = tid & 63;
  const int lr = lane & 15, lh = lane >> 4;
  const int bh = blockIdx.y, b = bh >> 3, h = bh & 7;
  const int q0 = blockIdx.x * 64;

  {
    const char* Kg = (const char*)(Kh + (size_t)bh * 16384);
    const char* Vg = (const char*)(Vt + (size_t)bh * 16384);
#pragma unroll
    for (int it = 0; it < 8; ++it) {
      const int e = it * 256 + tid;
      const int row = e >> 4;
      const int cb = (e & 15) << 4;
      const int dst = row * 256 + (cb ^ ((row & 7) << 4));
      *(uint4*)(Ks + dst) = *(const uint4*)(Kg + row * 256 + cb);
      *(uint4*)(Vs + dst) = *(const uint4*)(Vg + row * 256 + cb);
    }
  }
  if (tid < 128) Ms[tid] = (mask[b * 128 + tid] == 0) ? 0.f : 1.f;

  bf16x8 qf[4];
  {
    const bf16_t* Qb = Qh + ((size_t)bh * LQLEN + q0 + wid * 16 + lr) * 128;
#pragma unroll
    for (int s = 0; s < 4; ++s) qf[s] = *(const bf16x8*)(Qb + s * 32 + lh * 8);
  }
  __syncthreads();

  f32x4 acc[8] = {};
#pragma unroll
  for (int nt = 0; nt < 8; ++nt) {
#pragma unroll
    for (int s = 0; s < 4; ++s) {
      const int row = nt * 16 + lr;
      const int cb = (s * 64 + lh * 16) ^ ((row & 7) << 4);
      const bf16x8 kf = *(const bf16x8*)(Ks + row * 256 + cb);
      acc[nt] = __builtin_amdgcn_mfma_f32_16x16x32_bf16(qf[s], kf, acc[nt], 0, 0, 0);
    }
  }

  float ex[8][4];
  float rsum[4];
  const float sc = 0.08838834764831845f;
  const bf16_t* Ab = Ah + ((size_t)bh * LQLEN + q0 + wid * 16) * 128;
#pragma unroll
  for (int r = 0; r < 4; ++r) {
    const int row = lh * 4 + r;
    float mx = -3.0e38f;
#pragma unroll
    for (int nt = 0; nt < 8; ++nt) {
      const int col = nt * 16 + lr;
      float e = acc[nt][r] * sc + (float)Ab[row * 128 + col];
      e = (Ms[col] != 0.f) ? e : -1.0e10f;
      ex[nt][r] = e;
      mx = fmaxf(mx, e);
    }
    mx = fmaxf(mx, __shfl_xor(mx, 1));
    mx = fmaxf(mx, __shfl_xor(mx, 2));
    mx = fmaxf(mx, __shfl_xor(mx, 4));
    mx = fmaxf(mx, __shfl_xor(mx, 8));
    float s_ = 0.f;
#pragma unroll
    for (int nt = 0; nt < 8; ++nt) {
      const float p = expf(ex[nt][r] - mx);
      ex[nt][r] = p;
      s_ += p;
    }
    s_ += __shfl_xor(s_, 1);
    s_ += __shfl_xor(s_, 2);
    s_ += __shfl_xor(s_, 4);
    s_ += __shfl_xor(s_, 8);
    rsum[r] = s_;
  }

  __syncthreads();
  char* Pb = Ks + wid * 4096;
#pragma unroll
  for (int r = 0; r < 4; ++r) {
    const int row = lh * 4 + r;
#pragma unroll
    for (int nt = 0; nt < 8; ++nt) {
      const int col = nt * 16 + lr;
      const int off = (row * 256 + col * 2) ^ ((row & 7) << 4);
      *(bf16_t*)(Pb + off) = (bf16_t)ex[nt][r];
    }
  }
  __syncthreads();

  bf16x8 pf[4];
#pragma unroll
  for (int s = 0; s < 4; ++s)
    pf[s] = *(const bf16x8*)(Pb + lr * 256 + ((s * 64 + lh * 16) ^ ((lr & 7) << 4)));
  f32x4 acc2[8] = {};
#pragma unroll
  for (int nt = 0; nt < 8; ++nt) {
#pragma unroll
    for (int s = 0; s < 4; ++s) {
      const int row = nt * 16 + lr;
      const int cb = (s * 64 + lh * 16) ^ ((row & 7) << 4);
      const bf16x8 vf = *(const bf16x8*)(Vs + row * 256 + cb);
      acc2[nt] = __builtin_amdgcn_mfma_f32_16x16x32_bf16(pf[s], vf, acc2[nt], 0, 0, 0);
    }
  }

  float rs[4];
#pragma unroll
  for (int r = 0; r < 4; ++r) rs[r] = 1.f / rsum[r];
  bf16_t* Xb = X + ((size_t)b * LQLEN + q0 + wid * 16) * HIDN + h * 128;
#pragma unroll
  for (int nt = 0; nt < 8; ++nt)
#pragma unroll
    for (int r = 0; r < 4; ++r)
      Xb[(size_t)(lh * 4 + r) * HIDN + nt * 16 + lr] = (bf16_t)(acc2[nt][r] * rs[r]);
}

// ---------------------------------------------------------------------------
extern "C" void kernel_launch(void* const* d_in, const int* in_sizes, int n_in,
                              void* d_out, int out_size, void* d_ws, size_t ws_size,
                              hipStream_t stream) {
  const float* query = (const float*)d_in[0];
  const float* key   = (const float*)d_in[1];
  const float* value = (const float*)d_in[2];
  const float* atten = (const float*)d_in[3];
  const int*   mask  = (const int*)d_in[4];
  const float* Wq  = (const float*)d_in[5];  const float* bq   = (const float*)d_in[6];
  const float* Wk  = (const float*)d_in[7];  const float* bk   = (const float*)d_in[8];
  const float* Wv  = (const float*)d_in[9];  const float* bv   = (const float*)d_in[10];
  const float* Wat = (const float*)d_in[11]; const float* batt = (const float*)d_in[12];
  const float* Wfc = (const float*)d_in[13]; const float* bfc  = (const float*)d_in[14];

  char* ws = (char*)d_ws;
  bf16_t* qbf = (bf16_t*)(ws + 0x0000000);   // 64MB  [B,LQ,HID] bf16
  bf16_t* abf = (bf16_t*)(ws + 0x4000000);   // 64MB
  bf16_t* Qh  = (bf16_t*)(ws + 0x8000000);   // 64MB  [B,H,LQ,HD]
  bf16_t* Ah  = (bf16_t*)(ws + 0xC000000);   // 64MB
  char* sm = ws + 0x10000000;
  bf16_t* kbf = (bf16_t*)(sm + 0x000000);
  bf16_t* vbf = (bf16_t*)(sm + 0x200000);
  bf16_t* wqb = (bf16_t*)(sm + 0x400000);
  bf16_t* wkb = (bf16_t*)(sm + 0x600000);
  bf16_t* wvb = (bf16_t*)(sm + 0x800000);
  bf16_t* wab = (bf16_t*)(sm + 0xA00000);
  bf16_t* wfb = (bf16_t*)(sm + 0xC00000);
  bf16_t* Kh  = (bf16_t*)(sm + 0xE00000);    // [B,H,LK,HD]
  bf16_t* Vt  = (bf16_t*)(sm + 0x1000000);   // [B,H,HD,LK]
  bf16_t* X   = qbf;  // attention output reuses qbf (dead after Q-proj)

  auto conv = [&](const float* src, bf16_t* dst, int n) {
    const int n4 = n >> 2;
    int g = (n4 + 255) >> 8; if (g > 2048) g = 2048;
    convk<<<dim3(g), dim3(256), 0, stream>>>(src, dst, n4);
  };
  conv(query, qbf, NBATCH * LQLEN * HIDN);
  conv(atten, abf, NBATCH * LQLEN * HIDN);
  conv(key,   kbf, NBATCH * LKLEN * HIDN);
  conv(value, vbf, NBATCH * LKLEN * HIDN);
  conv(Wq,  wqb, HIDN * HIDN);
  conv(Wk,  wkb, HIDN * HIDN);
  conv(Wv,  wvb, HIDN * HIDN);
  conv(Wat, wab, HIDN * HIDN);
  conv(Wfc, wfb, HIDN * HIDN);

  // K/V projections (M = B*LK = 1024) — m97-structure kernel
  gemm_bt<0, 128><<<dim3(8, 8), dim3(256), 0, stream>>>(kbf, wkb, bk, (void*)Kh);
  gemm_bt<1, 128><<<dim3(8, 8), dim3(256), 0, stream>>>(vbf, wvb, bv, (void*)Vt);

  // Q / atten projections (M = 32768) — phased kernel
  gemm8p<0><<<dim3(1024), dim3(512), 0, stream>>>(qbf, wqb, bq, (void*)Qh);
  gemm8p<0><<<dim3(1024), dim3(512), 0, stream>>>(abf, wab, batt, (void*)Ah);

  // fused attention
  attn_kernel<<<dim3(LQLEN / 64, NBATCH * NHEAD), dim3(256), 0, stream>>>(
      Qh, Ah, Kh, Vt, mask, X);

  // final FC -> f32 out
  gemm8p<2><<<dim3(1024), dim3(512), 0, stream>>>(X, wfb, bfc, d_out);
}

// Round 3
// 476.614 us; speedup vs baseline: 1.0821x; 1.0019x over previous
//
#include <hip/hip_runtime.h>
#include <hip/hip_bf16.h>
#include <stdint.h>

typedef __bf16 bf16_t;
typedef __bf16 bf16x8 __attribute__((ext_vector_type(8)));
typedef __bf16 bf16x4 __attribute__((ext_vector_type(4)));
typedef float f32x4 __attribute__((ext_vector_type(4)));

// Problem constants
#define HIDN 1024
#define NHEAD 8
#define HDIM 128
#define NBATCH 8
#define LQLEN 4096
#define LKLEN 128

__device__ __forceinline__ void gload_lds16(const void* g, void* l) {
  __builtin_amdgcn_global_load_lds(
      (const __attribute__((address_space(1))) unsigned int*)g,
      (__attribute__((address_space(3))) unsigned int*)l, 16, 0, 0);
}

// ---------------------------------------------------------------------------
// f32 -> bf16 convert (vectorized float4 -> bf16x4)
// ---------------------------------------------------------------------------
__global__ __launch_bounds__(256) void convk(const float* __restrict__ in,
                                             bf16_t* __restrict__ out, int n4) {
  int i = blockIdx.x * blockDim.x + threadIdx.x;
  const int stride = gridDim.x * blockDim.x;
  for (; i < n4; i += stride) {
    const float4 v = ((const float4*)in)[i];
    bf16x4 o;
    o[0] = (bf16_t)v.x; o[1] = (bf16_t)v.y; o[2] = (bf16_t)v.z; o[3] = (bf16_t)v.w;
    ((bf16x4*)out)[i] = o;
  }
}

// ---------------------------------------------------------------------------
// Phased big GEMM: C[32768,1024] = A[32768,1024] @ Bw[1024,1024]^T + bias
// BM=128, BN=256, BK=64. 512 threads = 8 waves (2 x 4). Per-wave out 64x64.
// LDS: 3-slot ring, 48KB/slot (A 16KB + B 32KB) = 144KB (WAR-safe prefetch
// by construction: stage during tile t targets slot (t+2)%3=(t-1)%3 whose
// reads finished before tile t began).
// T2 swizzle (row stride 128B): logical (row, colb) stored at
//   row*128 + (colb ^ ((row&7)<<4))  -- spreads 16 same-col rows over 8
//   16B slots (2-way residual = free per m136). Applied BOTH sides:
//   linear LDS dest + inverse-swizzled global source + swizzled ds_read.
// T4: vmcnt(6) at tile boundaries; vmcnt(0) only at the last one.
// T5: setprio around MFMA clusters.
// XCD patch map: each XCD owns 32 m_blk x 4 n_blk, n fastest -> concurrent
//   L2 set = 8 A-panels (2MB) + 4 B-panels (2MB) fits 4MB XCD L2.
// MODE 0: bf16 head-layout store [B, H, 4096, 128];  MODE 2: f32 row-major.
// ---------------------------------------------------------------------------
template <int MODE>
__global__ __launch_bounds__(512, 2) void gemm8p(const bf16_t* __restrict__ A,
                                                 const bf16_t* __restrict__ Bw,
                                                 const float* __restrict__ bias,
                                                 void* __restrict__ Cout) {
  constexpr int NT = 16;       // K / 64
  constexpr int SLOT = 49152;  // 48KB
  __shared__ uint4 smem_raw[9216];  // 144KB
  char* smem = (char*)smem_raw;

  const int tid = threadIdx.x;
  const int wid = tid >> 6, lane = tid & 63;
  const int lr = lane & 15, lh = lane >> 4;
  const int wr = wid >> 2, wc = wid & 3;  // wave grid 2 (M) x 4 (N)

  // XCD patch mapping (1024 blocks, bijective)
  const int bid = blockIdx.x;
  const int m_blk = (bid & 7) * 32 + (bid >> 5);
  const int n_blk = (bid >> 3) & 3;
  const int m0 = m_blk * 128, n0 = n_blk * 256;

  // ---- staging map: thread tid covers 16B chunk tid (linear LDS).
  // LDS row = tid>>3, swizzled colb = (tid&7)<<4  ->  logical global col
  // = ((tid&7) ^ ((tid>>3)&7)) << 4.
  const int srow = tid >> 3;
  const int scolb = (((tid & 7) ^ ((tid >> 3) & 7)) << 4);
  const char* gA0 = (const char*)A + (size_t)(m0 + srow) * 2048 + scolb;
  const char* gA1 = gA0 + (size_t)64 * 2048;
  const char* gB0 = (const char*)Bw + (size_t)(n0 + srow) * 2048 + scolb;
  const char* gB1 = gB0 + (size_t)64 * 2048;
  const char* gB2 = gB0 + (size_t)128 * 2048;
  const char* gB3 = gB0 + (size_t)192 * 2048;
  const int dA0 = tid * 16, dA1 = 8192 + tid * 16;
  const int dB0 = 16384 + tid * 16, dB1 = 24576 + tid * 16;
  const int dB2 = 32768 + tid * 16, dB3 = 40960 + tid * 16;

  // ---- read-side: fragment row has row&7 == lr&7 (wave/f offsets are %8==0)
  const int sw = (lr & 7) << 4;
  const int arow0 = wr * 64 + lr;
  const int brow0 = wc * 64 + lr;

  f32x4 acc[4][4] = {};

  // ---- prologue: stage tiles 0,1; wait until tile 0 landed (6 outstanding)
#pragma unroll
  for (int tt = 0; tt < 2; ++tt) {
    char* dst = smem + tt * SLOT;
    const int kb = tt * 128;
    gload_lds16(gA0 + kb, dst + dA0);
    gload_lds16(gA1 + kb, dst + dA1);
    gload_lds16(gB0 + kb, dst + dB0);
    gload_lds16(gB1 + kb, dst + dB1);
    gload_lds16(gB2 + kb, dst + dB2);
    gload_lds16(gB3 + kb, dst + dB3);
  }
  asm volatile("s_waitcnt vmcnt(6)" ::: "memory");
  __builtin_amdgcn_s_barrier();

  for (int t = 0; t < NT; ++t) {
    const char* sA = smem + (t % 3) * SLOT;
    const char* sB = sA + 16384;
    char* dst = smem + ((t + 2) % 3) * SLOT;
    const int kb = (t + 2) * 128;
    const bool pf = (t < NT - 2);

    // ===== phase 0: issue B(all) + A(f0,f1) reads, 3 stage loads ===========
    bf16x8 bfrag[4][2], af[2][2];
#pragma unroll
    for (int j = 0; j < 4; ++j)
#pragma unroll
      for (int kk = 0; kk < 2; ++kk)
        bfrag[j][kk] = *(const bf16x8*)(sB + (brow0 + j * 16) * 128 + (((kk << 6) | (lh << 4)) ^ sw));
#pragma unroll
    for (int f = 0; f < 2; ++f)
#pragma unroll
      for (int kk = 0; kk < 2; ++kk)
        af[f][kk] = *(const bf16x8*)(sA + (arow0 + f * 16) * 128 + (((kk << 6) | (lh << 4)) ^ sw));
    if (pf) {
      gload_lds16(gA0 + kb, dst + dA0);
      gload_lds16(gA1 + kb, dst + dA1);
      gload_lds16(gB0 + kb, dst + dB0);
    }
    __builtin_amdgcn_s_barrier();
    asm volatile("s_waitcnt lgkmcnt(0)" ::: "memory");
    __builtin_amdgcn_s_setprio(1);
#pragma unroll
    for (int f = 0; f < 2; ++f)
#pragma unroll
      for (int j = 0; j < 4; ++j)
#pragma unroll
        for (int kk = 0; kk < 2; ++kk)
          acc[f][j] = __builtin_amdgcn_mfma_f32_16x16x32_bf16(af[f][kk], bfrag[j][kk], acc[f][j], 0, 0, 0);
    __builtin_amdgcn_s_setprio(0);
    __builtin_amdgcn_s_barrier();

    // ===== phase 1: issue A(f2,f3) reads, 3 stage loads ====================
#pragma unroll
    for (int f = 0; f < 2; ++f)
#pragma unroll
      for (int kk = 0; kk < 2; ++kk)
        af[f][kk] = *(const bf16x8*)(sA + (arow0 + (f + 2) * 16) * 128 + (((kk << 6) | (lh << 4)) ^ sw));
    if (pf) {
      gload_lds16(gB1 + kb, dst + dB1);
      gload_lds16(gB2 + kb, dst + dB2);
      gload_lds16(gB3 + kb, dst + dB3);
    }
    __builtin_amdgcn_s_barrier();
    asm volatile("s_waitcnt lgkmcnt(0)" ::: "memory");
    __builtin_amdgcn_s_setprio(1);
#pragma unroll
    for (int f = 0; f < 2; ++f)
#pragma unroll
      for (int j = 0; j < 4; ++j)
#pragma unroll
        for (int kk = 0; kk < 2; ++kk)
          acc[f + 2][j] = __builtin_amdgcn_mfma_f32_16x16x32_bf16(af[f][kk], bfrag[j][kk], acc[f + 2][j], 0, 0, 0);
    __builtin_amdgcn_s_setprio(0);

    // ===== tile boundary: counted vmcnt, full drain only at the end ========
    if (t < NT - 1) {
      __builtin_amdgcn_sched_barrier(0);
      if (t == NT - 2)
        asm volatile("s_waitcnt vmcnt(0) lgkmcnt(0)" ::: "memory");
      else
        asm volatile("s_waitcnt vmcnt(6) lgkmcnt(0)" ::: "memory");
      __builtin_amdgcn_s_barrier();
    }
  }

  // ---- epilogue. C/D layout: col = lane&15, row = (lane>>4)*4 + reg.
  if constexpr (MODE == 2) {
    float* C = (float*)Cout;
#pragma unroll
    for (int f = 0; f < 4; ++f) {
      const int gm = m0 + wr * 64 + f * 16 + lh * 4;
#pragma unroll
      for (int j = 0; j < 4; ++j) {
        const int gn = n0 + wc * 64 + j * 16 + lr;
        const float bb = bias[gn];
#pragma unroll
        for (int r = 0; r < 4; ++r)
          C[(size_t)(gm + r) * HIDN + gn] = acc[f][j][r] + bb;
      }
    }
  } else {
    bf16_t* C = (bf16_t*)Cout;
#pragma unroll
    for (int f = 0; f < 4; ++f) {
      const int gm = m0 + wr * 64 + f * 16 + lh * 4;
#pragma unroll
      for (int j = 0; j < 4; ++j) {
        const int gn = n0 + wc * 64 + j * 16 + lr;
        const float bb = bias[gn];
        const int h = gn >> 7, d = gn & 127;
#pragma unroll
        for (int r = 0; r < 4; ++r) {
          const int b = (gm + r) >> 12, l = (gm + r) & 4095;
          C[(((size_t)(b * NHEAD + h) * LQLEN + l) << 7) + d] = (bf16_t)(acc[f][j][r] + bb);
        }
      }
    }
  }
}

// ---------------------------------------------------------------------------
// Small GEMM (m97 structure) for the K/V projections (M = 1024 only)
// MODE 0: bf16 head-layout store  [B, H, LROW, 128]   (Kh)
// MODE 1: bf16 transposed head    [B, H, 128, LROW]   (Vt; LROW==128)
// ---------------------------------------------------------------------------
template <int MODE, int LROW>
__global__ __launch_bounds__(256) void gemm_bt(const bf16_t* __restrict__ A,
                                               const bf16_t* __restrict__ Bw,
                                               const float* __restrict__ bias,
                                               void* __restrict__ Cout) {
  constexpr int BK = 32;
  __shared__ uint4 AsRaw[128 * BK * 2 / 16];
  __shared__ uint4 BsRaw[128 * BK * 2 / 16];
  bf16_t* As = (bf16_t*)AsRaw;
  bf16_t* Bs = (bf16_t*)BsRaw;

  const int tid = threadIdx.x;
  const int wid = tid >> 6;
  const int lane = tid & 63;
  const int lr = lane & 15, lh = lane >> 4;
  const int m0 = blockIdx.x * 128, n0 = blockIdx.y * 128;
  const int wm = (wid >> 1) * 64, wn = (wid & 1) * 64;

  f32x4 acc[4][4] = {};

  const int srow = lane >> 2;
  const int scol = (lane & 3) * 16;

  for (int k0 = 0; k0 < HIDN; k0 += BK) {
#pragma unroll
    for (int i = 0; i < 2; ++i) {
      const int c = wid + i * 4;
      const int row = c * 16 + srow;
      gload_lds16((const char*)A + ((size_t)(m0 + row) * HIDN + k0) * 2 + scol,
                  (char*)As + c * 1024);
      gload_lds16((const char*)Bw + ((size_t)(n0 + row) * HIDN + k0) * 2 + scol,
                  (char*)Bs + c * 1024);
    }
    __syncthreads();

    bf16x8 af[4], bfr[4];
#pragma unroll
    for (int i = 0; i < 4; ++i) {
      af[i]  = *(const bf16x8*)(As + (wm + i * 16 + lr) * BK + lh * 8);
      bfr[i] = *(const bf16x8*)(Bs + (wn + i * 16 + lr) * BK + lh * 8);
    }
#pragma unroll
    for (int i = 0; i < 4; ++i)
#pragma unroll
      for (int j = 0; j < 4; ++j)
        acc[i][j] = __builtin_amdgcn_mfma_f32_16x16x32_bf16(af[i], bfr[j], acc[i][j], 0, 0, 0);
    __syncthreads();
  }

#pragma unroll
  for (int i = 0; i < 4; ++i) {
#pragma unroll
    for (int r = 0; r < 4; ++r) {
      const int gm = m0 + wm + i * 16 + lh * 4 + r;
#pragma unroll
      for (int j = 0; j < 4; ++j) {
        const int gn = n0 + wn + j * 16 + lr;
        const float v = acc[i][j][r] + bias[gn];
        const int b = gm / LROW, l = gm - b * LROW;
        const int h = gn >> 7, d = gn & 127;
        size_t idx;
        if constexpr (MODE == 0)
          idx = (((size_t)(b * NHEAD + h) * LROW + l) << 7) + d;
        else
          idx = (((size_t)(b * NHEAD + h) * 128 + d) << 7) + l;
        ((bf16_t*)Cout)[idx] = (bf16_t)v;
      }
    }
  }
}

// ---------------------------------------------------------------------------
// Fused attention: energy = QK^T/sqrt(128) + Ah, mask, softmax, x = P V
// ---------------------------------------------------------------------------
__global__ __launch_bounds__(256) void attn_kernel(
    const bf16_t* __restrict__ Qh, const bf16_t* __restrict__ Ah,
    const bf16_t* __restrict__ Kh, const bf16_t* __restrict__ Vt,
    const int* __restrict__ mask, bf16_t* __restrict__ X) {
  __shared__ uint4 KsRaw[2048];
  __shared__ uint4 VsRaw[2048];
  __shared__ float Ms[128];
  char* Ks = (char*)KsRaw;
  char* Vs = (char*)VsRaw;

  const int tid = threadIdx.x, wid = tid >> 6, lane = tid & 63;
  const int lr = lane & 15, lh = lane >> 4;
  const int bh = blockIdx.y, b = bh >> 3, h = bh & 7;
  const int q0 = blockIdx.x * 64;

  {
    const char* Kg = (const char*)(Kh + (size_t)bh * 16384);
    const char* Vg = (const char*)(Vt + (size_t)bh * 16384);
#pragma unroll
    for (int it = 0; it < 8; ++it) {
      const int e = it * 256 + tid;
      const int row = e >> 4;
      const int cb = (e & 15) << 4;
      const int dst = row * 256 + (cb ^ ((row & 7) << 4));
      *(uint4*)(Ks + dst) = *(const uint4*)(Kg + row * 256 + cb);
      *(uint4*)(Vs + dst) = *(const uint4*)(Vg + row * 256 + cb);
    }
  }
  if (tid < 128) Ms[tid] = (mask[b * 128 + tid] == 0) ? 0.f : 1.f;

  bf16x8 qf[4];
  {
    const bf16_t* Qb = Qh + ((size_t)bh * LQLEN + q0 + wid * 16 + lr) * 128;
#pragma unroll
    for (int s = 0; s < 4; ++s) qf[s] = *(const bf16x8*)(Qb + s * 32 + lh * 8);
  }
  __syncthreads();

  f32x4 acc[8] = {};
#pragma unroll
  for (int nt = 0; nt < 8; ++nt) {
#pragma unroll
    for (int s = 0; s < 4; ++s) {
      const int row = nt * 16 + lr;
      const int cb = (s * 64 + lh * 16) ^ ((row & 7) << 4);
      const bf16x8 kf = *(const bf16x8*)(Ks + row * 256 + cb);
      acc[nt] = __builtin_amdgcn_mfma_f32_16x16x32_bf16(qf[s], kf, acc[nt], 0, 0, 0);
    }
  }

  float ex[8][4];
  float rsum[4];
  const float sc = 0.08838834764831845f;
  const bf16_t* Ab = Ah + ((size_t)bh * LQLEN + q0 + wid * 16) * 128;
#pragma unroll
  for (int r = 0; r < 4; ++r) {
    const int row = lh * 4 + r;
    float mx = -3.0e38f;
#pragma unroll
    for (int nt = 0; nt < 8; ++nt) {
      const int col = nt * 16 + lr;
      float e = acc[nt][r] * sc + (float)Ab[row * 128 + col];
      e = (Ms[col] != 0.f) ? e : -1.0e10f;
      ex[nt][r] = e;
      mx = fmaxf(mx, e);
    }
    mx = fmaxf(mx, __shfl_xor(mx, 1));
    mx = fmaxf(mx, __shfl_xor(mx, 2));
    mx = fmaxf(mx, __shfl_xor(mx, 4));
    mx = fmaxf(mx, __shfl_xor(mx, 8));
    float s_ = 0.f;
#pragma unroll
    for (int nt = 0; nt < 8; ++nt) {
      const float p = expf(ex[nt][r] - mx);
      ex[nt][r] = p;
      s_ += p;
    }
    s_ += __shfl_xor(s_, 1);
    s_ += __shfl_xor(s_, 2);
    s_ += __shfl_xor(s_, 4);
    s_ += __shfl_xor(s_, 8);
    rsum[r] = s_;
  }

  __syncthreads();
  char* Pb = Ks + wid * 4096;
#pragma unroll
  for (int r = 0; r < 4; ++r) {
    const int row = lh * 4 + r;
#pragma unroll
    for (int nt = 0; nt < 8; ++nt) {
      const int col = nt * 16 + lr;
      const int off = (row * 256 + col * 2) ^ ((row & 7) << 4);
      *(bf16_t*)(Pb + off) = (bf16_t)ex[nt][r];
    }
  }
  __syncthreads();

  bf16x8 pf[4];
#pragma unroll
  for (int s = 0; s < 4; ++s)
    pf[s] = *(const bf16x8*)(Pb + lr * 256 + ((s * 64 + lh * 16) ^ ((lr & 7) << 4)));
  f32x4 acc2[8] = {};
#pragma unroll
  for (int nt = 0; nt < 8; ++nt) {
#pragma unroll
    for (int s = 0; s < 4; ++s) {
      const int row = nt * 16 + lr;
      const int cb = (s * 64 + lh * 16) ^ ((row & 7) << 4);
      const bf16x8 vf = *(const bf16x8*)(Vs + row * 256 + cb);
      acc2[nt] = __builtin_amdgcn_mfma_f32_16x16x32_bf16(pf[s], vf, acc2[nt], 0, 0, 0);
    }
  }

  float rs[4];
#pragma unroll
  for (int r = 0; r < 4; ++r) rs[r] = 1.f / rsum[r];
  bf16_t* Xb = X + ((size_t)b * LQLEN + q0 + wid * 16) * HIDN + h * 128;
#pragma unroll
  for (int nt = 0; nt < 8; ++nt)
#pragma unroll
    for (int r = 0; r < 4; ++r)
      Xb[(size_t)(lh * 4 + r) * HIDN + nt * 16 + lr] = (bf16_t)(acc2[nt][r] * rs[r]);
}

// ---------------------------------------------------------------------------
extern "C" void kernel_launch(void* const* d_in, const int* in_sizes, int n_in,
                              void* d_out, int out_size, void* d_ws, size_t ws_size,
                              hipStream_t stream) {
  const float* query = (const float*)d_in[0];
  const float* key   = (const float*)d_in[1];
  const float* value = (const float*)d_in[2];
  const float* atten = (const float*)d_in[3];
  const int*   mask  = (const int*)d_in[4];
  const float* Wq  = (const float*)d_in[5];  const float* bq   = (const float*)d_in[6];
  const float* Wk  = (const float*)d_in[7];  const float* bk   = (const float*)d_in[8];
  const float* Wv  = (const float*)d_in[9];  const float* bv   = (const float*)d_in[10];
  const float* Wat = (const float*)d_in[11]; const float* batt = (const float*)d_in[12];
  const float* Wfc = (const float*)d_in[13]; const float* bfc  = (const float*)d_in[14];

  char* ws = (char*)d_ws;
  bf16_t* qbf = (bf16_t*)(ws + 0x0000000);   // 64MB  [B,LQ,HID] bf16
  bf16_t* abf = (bf16_t*)(ws + 0x4000000);   // 64MB
  bf16_t* Qh  = (bf16_t*)(ws + 0x8000000);   // 64MB  [B,H,LQ,HD]
  bf16_t* Ah  = (bf16_t*)(ws + 0xC000000);   // 64MB
  char* sm = ws + 0x10000000;
  bf16_t* kbf = (bf16_t*)(sm + 0x000000);
  bf16_t* vbf = (bf16_t*)(sm + 0x200000);
  bf16_t* wqb = (bf16_t*)(sm + 0x400000);
  bf16_t* wkb = (bf16_t*)(sm + 0x600000);
  bf16_t* wvb = (bf16_t*)(sm + 0x800000);
  bf16_t* wab = (bf16_t*)(sm + 0xA00000);
  bf16_t* wfb = (bf16_t*)(sm + 0xC00000);
  bf16_t* Kh  = (bf16_t*)(sm + 0xE00000);    // [B,H,LK,HD]
  bf16_t* Vt  = (bf16_t*)(sm + 0x1000000);   // [B,H,HD,LK]
  bf16_t* X   = qbf;  // attention output reuses qbf (dead after Q-proj)

  auto conv = [&](const float* src, bf16_t* dst, int n) {
    const int n4 = n >> 2;
    int g = (n4 + 255) >> 8; if (g > 2048) g = 2048;
    convk<<<dim3(g), dim3(256), 0, stream>>>(src, dst, n4);
  };
  conv(query, qbf, NBATCH * LQLEN * HIDN);
  conv(atten, abf, NBATCH * LQLEN * HIDN);
  conv(key,   kbf, NBATCH * LKLEN * HIDN);
  conv(value, vbf, NBATCH * LKLEN * HIDN);
  conv(Wq,  wqb, HIDN * HIDN);
  conv(Wk,  wkb, HIDN * HIDN);
  conv(Wv,  wvb, HIDN * HIDN);
  conv(Wat, wab, HIDN * HIDN);
  conv(Wfc, wfb, HIDN * HIDN);

  // K/V projections (M = B*LK = 1024) — m97-structure kernel
  gemm_bt<0, 128><<<dim3(8, 8), dim3(256), 0, stream>>>(kbf, wkb, bk, (void*)Kh);
  gemm_bt<1, 128><<<dim3(8, 8), dim3(256), 0, stream>>>(vbf, wvb, bv, (void*)Vt);

  // Q / atten projections (M = 32768) — phased kernel
  gemm8p<0><<<dim3(1024), dim3(512), 0, stream>>>(qbf, wqb, bq, (void*)Qh);
  gemm8p<0><<<dim3(1024), dim3(512), 0, stream>>>(abf, wab, batt, (void*)Ah);

  // fused attention
  attn_kernel<<<dim3(LQLEN / 64, NBATCH * NHEAD), dim3(256), 0, stream>>>(
      Qh, Ah, Kh, Vt, mask, X);

  // final FC -> f32 out
  gemm8p<2><<<dim3(1024), dim3(512), 0, stream>>>(X, wfb, bfc, d_out);
}

// Round 4
// 470.701 us; speedup vs baseline: 1.0957x; 1.0126x over previous
//
#include <hip/hip_runtime.h>
#include <hip/hip_bf16.h>
#include <stdint.h>

typedef __bf16 bf16_t;
typedef __bf16 bf16x8 __attribute__((ext_vector_type(8)));
typedef __bf16 bf16x4 __attribute__((ext_vector_type(4)));
typedef float f32x4 __attribute__((ext_vector_type(4)));

// Problem constants
#define HIDN 1024
#define NHEAD 8
#define HDIM 128
#define NBATCH 8
#define LQLEN 4096
#define LKLEN 128

__device__ __forceinline__ void gload_lds16(const void* g, void* l) {
  __builtin_amdgcn_global_load_lds(
      (const __attribute__((address_space(1))) unsigned int*)g,
      (__attribute__((address_space(3))) unsigned int*)l, 16, 0, 0);
}

// ---------------------------------------------------------------------------
// f32 -> bf16 convert (vectorized float4 -> bf16x4)
// ---------------------------------------------------------------------------
__global__ __launch_bounds__(256) void convk(const float* __restrict__ in,
                                             bf16_t* __restrict__ out, int n4) {
  int i = blockIdx.x * blockDim.x + threadIdx.x;
  const int stride = gridDim.x * blockDim.x;
  for (; i < n4; i += stride) {
    const float4 v = ((const float4*)in)[i];
    bf16x4 o;
    o[0] = (bf16_t)v.x; o[1] = (bf16_t)v.y; o[2] = (bf16_t)v.z; o[3] = (bf16_t)v.w;
    ((bf16x4*)out)[i] = o;
  }
}

// ---------------------------------------------------------------------------
// Phased big GEMM: C[32768,1024] = A[32768,1024] @ Bw[1024,1024]^T + bias
// BM=BN=256, BK=32. 512 threads = 8 waves (2M x 4N), wave-tile 128x64
//   (reads/MFMA = 0.375 -> LDS-pipe ceiling ~60% vs 44% for 64x64 waves).
// BK=32 => 64B LDS row stride: 16x16x32 fragment reads are NATURALLY
//   bank-balanced (bank = 16*lr + 4*lh mod 32) -> no swizzle, linear
//   global_load_lds staging.
// LDS ring-of-4 (4 x 32KB = 128KB): during tile t stage tile t+3 into slot
//   (t+3)&3 = (t-1)&3 whose reads finished before tile t began (WAR-safe by
//   construction). Boundary s_waitcnt vmcnt(8) keeps 2 tiles in flight
//   (~1000 cyc HBM tolerance); vmcnt(4)/(0) only in the final drain.
// Per tile: ph0 {read B(4)+A m0-3(4), stage A(t+3), bar, lgkm0, 16 MFMA,
//   bar}; ph1 {read A m4-7(4), stage B(t+3), bar, lgkm0, 16 MFMA};
//   boundary {vmcnt(N), bar}.  T5 setprio around MFMA clusters.
// MODE 0: bf16 head-layout store [B, H, 4096, 128];  MODE 2: f32 row-major.
// ---------------------------------------------------------------------------
template <int MODE>
__global__ __launch_bounds__(512, 2) void gemm8p(const bf16_t* __restrict__ A,
                                                 const bf16_t* __restrict__ Bw,
                                                 const float* __restrict__ bias,
                                                 void* __restrict__ Cout) {
  constexpr int NT = 32;       // K / 32
  constexpr int SLOT = 32768;  // A 16KB + B 16KB
  __shared__ uint4 smem_raw[8192];  // 128KB
  char* smem = (char*)smem_raw;

  const int tid = threadIdx.x;
  const int wid = tid >> 6, lane = tid & 63;
  const int lr = lane & 15, lh = lane >> 4;
  const int wr = wid >> 2, wc = wid & 3;  // wave grid 2 (M) x 4 (N)

  // XCD patch mapping (512 blocks, bijective; n fastest within XCD)
  const int bid = blockIdx.x;
  const int m_blk = (bid & 7) * 16 + (bid >> 5);
  const int n_blk = (bid >> 3) & 3;
  const int m0 = m_blk * 256, n0 = n_blk * 256;

  // ---- staging map: chunk c = tid (+512) -> row c>>2, 16B col (c&3)*16.
  const int c0 = tid, c1 = tid + 512;
  const char* srcA0 = (const char*)A + (size_t)(m0 + (c0 >> 2)) * 2048 + ((c0 & 3) << 4);
  const char* srcA1 = (const char*)A + (size_t)(m0 + (c1 >> 2)) * 2048 + ((c1 & 3) << 4);
  const char* srcB0 = (const char*)Bw + (size_t)(n0 + (c0 >> 2)) * 2048 + ((c0 & 3) << 4);
  const char* srcB1 = (const char*)Bw + (size_t)(n0 + (c1 >> 2)) * 2048 + ((c1 & 3) << 4);
  const int d0 = c0 * 16, d1 = c1 * 16;

  f32x4 acc[8][4] = {};

  // ---- prologue: stage tiles 0,1,2; wait tile 0 (8 outstanding = t1,t2)
#pragma unroll
  for (int tt = 0; tt < 3; ++tt) {
    char* dst = smem + tt * SLOT;
    gload_lds16(srcA0 + tt * 64, dst + d0);
    gload_lds16(srcA1 + tt * 64, dst + d1);
    gload_lds16(srcB0 + tt * 64, dst + 16384 + d0);
    gload_lds16(srcB1 + tt * 64, dst + 16384 + d1);
  }
  asm volatile("s_waitcnt vmcnt(8)" ::: "memory");
  __builtin_amdgcn_s_barrier();

  const int aoff = (wr * 128 + lr) * 64 + lh * 16;
  const int boff = 16384 + (wc * 64 + lr) * 64 + lh * 16;

  for (int t = 0; t < NT; ++t) {
    const char* sA = smem + (t & 3) * SLOT + aoff;
    const char* sB = smem + (t & 3) * SLOT + boff;
    char* dst = smem + ((t + 3) & 3) * SLOT;
    const int kb = (t + 3) * 64;
    const bool pf = (t <= NT - 4);

    // ===== phase 0: read B(n0-3) + A(m0-3); stage A(t+3) ===================
    bf16x8 bfr[4], af0[4];
#pragma unroll
    for (int n = 0; n < 4; ++n) bfr[n] = *(const bf16x8*)(sB + n * 1024);
#pragma unroll
    for (int m = 0; m < 4; ++m) af0[m] = *(const bf16x8*)(sA + m * 1024);
    if (pf) {
      gload_lds16(srcA0 + kb, dst + d0);
      gload_lds16(srcA1 + kb, dst + d1);
    }
    __builtin_amdgcn_s_barrier();
    asm volatile("s_waitcnt lgkmcnt(0)" ::: "memory");
    __builtin_amdgcn_sched_barrier(0);
    __builtin_amdgcn_s_setprio(1);
#pragma unroll
    for (int m = 0; m < 4; ++m)
#pragma unroll
      for (int n = 0; n < 4; ++n)
        acc[m][n] = __builtin_amdgcn_mfma_f32_16x16x32_bf16(af0[m], bfr[n], acc[m][n], 0, 0, 0);
    __builtin_amdgcn_s_setprio(0);
    __builtin_amdgcn_s_barrier();

    // ===== phase 1: read A(m4-7); stage B(t+3) =============================
    bf16x8 af1[4];
#pragma unroll
    for (int m = 0; m < 4; ++m) af1[m] = *(const bf16x8*)(sA + (m + 4) * 1024);
    if (pf) {
      gload_lds16(srcB0 + kb, dst + 16384 + d0);
      gload_lds16(srcB1 + kb, dst + 16384 + d1);
    }
    __builtin_amdgcn_s_barrier();
    asm volatile("s_waitcnt lgkmcnt(0)" ::: "memory");
    __builtin_amdgcn_sched_barrier(0);
    __builtin_amdgcn_s_setprio(1);
#pragma unroll
    for (int m = 0; m < 4; ++m)
#pragma unroll
      for (int n = 0; n < 4; ++n)
        acc[m + 4][n] = __builtin_amdgcn_mfma_f32_16x16x32_bf16(af1[m], bfr[n], acc[m + 4][n], 0, 0, 0);
    __builtin_amdgcn_s_setprio(0);

    // ===== tile boundary: counted vmcnt (8 = 2 tiles in flight) ============
    if (t < NT - 1) {
      __builtin_amdgcn_sched_barrier(0);
      if (t <= NT - 4)
        asm volatile("s_waitcnt vmcnt(8)" ::: "memory");
      else if (t == NT - 3)
        asm volatile("s_waitcnt vmcnt(4)" ::: "memory");
      else
        asm volatile("s_waitcnt vmcnt(0)" ::: "memory");
      __builtin_amdgcn_sched_barrier(0);
      __builtin_amdgcn_s_barrier();
    }
  }

  // ---- epilogue. C/D layout: col = lane&15, row = (lane>>4)*4 + reg.
  if constexpr (MODE == 2) {
    float* C = (float*)Cout;
#pragma unroll
    for (int f = 0; f < 8; ++f) {
      const int gm = m0 + wr * 128 + f * 16 + lh * 4;
#pragma unroll
      for (int j = 0; j < 4; ++j) {
        const int gn = n0 + wc * 64 + j * 16 + lr;
        const float bb = bias[gn];
#pragma unroll
        for (int r = 0; r < 4; ++r)
          C[(size_t)(gm + r) * HIDN + gn] = acc[f][j][r] + bb;
      }
    }
  } else {
    bf16_t* C = (bf16_t*)Cout;
#pragma unroll
    for (int f = 0; f < 8; ++f) {
      const int gm = m0 + wr * 128 + f * 16 + lh * 4;
#pragma unroll
      for (int j = 0; j < 4; ++j) {
        const int gn = n0 + wc * 64 + j * 16 + lr;
        const float bb = bias[gn];
        const int h = gn >> 7, d = gn & 127;
#pragma unroll
        for (int r = 0; r < 4; ++r) {
          const int b = (gm + r) >> 12, l = (gm + r) & 4095;
          C[(((size_t)(b * NHEAD + h) * LQLEN + l) << 7) + d] = (bf16_t)(acc[f][j][r] + bb);
        }
      }
    }
  }
}

// ---------------------------------------------------------------------------
// Small GEMM (m97 structure) for the K/V projections (M = 1024 only)
// MODE 0: bf16 head-layout store  [B, H, LROW, 128]   (Kh)
// MODE 1: bf16 transposed head    [B, H, 128, LROW]   (Vt; LROW==128)
// ---------------------------------------------------------------------------
template <int MODE, int LROW>
__global__ __launch_bounds__(256) void gemm_bt(const bf16_t* __restrict__ A,
                                               const bf16_t* __restrict__ Bw,
                                               const float* __restrict__ bias,
                                               void* __restrict__ Cout) {
  constexpr int BK = 32;
  __shared__ uint4 AsRaw[128 * BK * 2 / 16];
  __shared__ uint4 BsRaw[128 * BK * 2 / 16];
  bf16_t* As = (bf16_t*)AsRaw;
  bf16_t* Bs = (bf16_t*)BsRaw;

  const int tid = threadIdx.x;
  const int wid = tid >> 6;
  const int lane = tid & 63;
  const int lr = lane & 15, lh = lane >> 4;
  const int m0 = blockIdx.x * 128, n0 = blockIdx.y * 128;
  const int wm = (wid >> 1) * 64, wn = (wid & 1) * 64;

  f32x4 acc[4][4] = {};

  const int srow = lane >> 2;
  const int scol = (lane & 3) * 16;

  for (int k0 = 0; k0 < HIDN; k0 += BK) {
#pragma unroll
    for (int i = 0; i < 2; ++i) {
      const int c = wid + i * 4;
      const int row = c * 16 + srow;
      gload_lds16((const char*)A + ((size_t)(m0 + row) * HIDN + k0) * 2 + scol,
                  (char*)As + c * 1024);
      gload_lds16((const char*)Bw + ((size_t)(n0 + row) * HIDN + k0) * 2 + scol,
                  (char*)Bs + c * 1024);
    }
    __syncthreads();

    bf16x8 af[4], bfr[4];
#pragma unroll
    for (int i = 0; i < 4; ++i) {
      af[i]  = *(const bf16x8*)(As + (wm + i * 16 + lr) * BK + lh * 8);
      bfr[i] = *(const bf16x8*)(Bs + (wn + i * 16 + lr) * BK + lh * 8);
    }
#pragma unroll
    for (int i = 0; i < 4; ++i)
#pragma unroll
      for (int j = 0; j < 4; ++j)
        acc[i][j] = __builtin_amdgcn_mfma_f32_16x16x32_bf16(af[i], bfr[j], acc[i][j], 0, 0, 0);
    __syncthreads();
  }

#pragma unroll
  for (int i = 0; i < 4; ++i) {
#pragma unroll
    for (int r = 0; r < 4; ++r) {
      const int gm = m0 + wm + i * 16 + lh * 4 + r;
#pragma unroll
      for (int j = 0; j < 4; ++j) {
        const int gn = n0 + wn + j * 16 + lr;
        const float v = acc[i][j][r] + bias[gn];
        const int b = gm / LROW, l = gm - b * LROW;
        const int h = gn >> 7, d = gn & 127;
        size_t idx;
        if constexpr (MODE == 0)
          idx = (((size_t)(b * NHEAD + h) * LROW + l) << 7) + d;
        else
          idx = (((size_t)(b * NHEAD + h) * 128 + d) << 7) + l;
        ((bf16_t*)Cout)[idx] = (bf16_t)v;
      }
    }
  }
}

// ---------------------------------------------------------------------------
// Fused attention: energy = QK^T/sqrt(128) + Ah, mask, softmax, x = P V
// ---------------------------------------------------------------------------
__global__ __launch_bounds__(256) void attn_kernel(
    const bf16_t* __restrict__ Qh, const bf16_t* __restrict__ Ah,
    const bf16_t* __restrict__ Kh, const bf16_t* __restrict__ Vt,
    const int* __restrict__ mask, bf16_t* __restrict__ X) {
  __shared__ uint4 KsRaw[2048];
  __shared__ uint4 VsRaw[2048];
  __shared__ float Ms[128];
  char* Ks = (char*)KsRaw;
  char* Vs = (char*)VsRaw;

  const int tid = threadIdx.x, wid = tid >> 6, lane = tid & 63;
  const int lr = lane & 15, lh = lane >> 4;
  const int bh = blockIdx.y, b = bh >> 3, h = bh & 7;
  const int q0 = blockIdx.x * 64;

  {
    const char* Kg = (const char*)(Kh + (size_t)bh * 16384);
    const char* Vg = (const char*)(Vt + (size_t)bh * 16384);
#pragma unroll
    for (int it = 0; it < 8; ++it) {
      const int e = it * 256 + tid;
      const int row = e >> 4;
      const int cb = (e & 15) << 4;
      const int dst = row * 256 + (cb ^ ((row & 7) << 4));
      *(uint4*)(Ks + dst) = *(const uint4*)(Kg + row * 256 + cb);
      *(uint4*)(Vs + dst) = *(const uint4*)(Vg + row * 256 + cb);
    }
  }
  if (tid < 128) Ms[tid] = (mask[b * 128 + tid] == 0) ? 0.f : 1.f;

  bf16x8 qf[4];
  {
    const bf16_t* Qb = Qh + ((size_t)bh * LQLEN + q0 + wid * 16 + lr) * 128;
#pragma unroll
    for (int s = 0; s < 4; ++s) qf[s] = *(const bf16x8*)(Qb + s * 32 + lh * 8);
  }
  __syncthreads();

  f32x4 acc[8] = {};
#pragma unroll
  for (int nt = 0; nt < 8; ++nt) {
#pragma unroll
    for (int s = 0; s < 4; ++s) {
      const int row = nt * 16 + lr;
      const int cb = (s * 64 + lh * 16) ^ ((row & 7) << 4);
      const bf16x8 kf = *(const bf16x8*)(Ks + row * 256 + cb);
      acc[nt] = __builtin_amdgcn_mfma_f32_16x16x32_bf16(qf[s], kf, acc[nt], 0, 0, 0);
    }
  }

  float ex[8][4];
  float rsum[4];
  const float sc = 0.08838834764831845f;
  const bf16_t* Ab = Ah + ((size_t)bh * LQLEN + q0 + wid * 16) * 128;
#pragma unroll
  for (int r = 0; r < 4; ++r) {
    const int row = lh * 4 + r;
    float mx = -3.0e38f;
#pragma unroll
    for (int nt = 0; nt < 8; ++nt) {
      const int col = nt * 16 + lr;
      float e = acc[nt][r] * sc + (float)Ab[row * 128 + col];
      e = (Ms[col] != 0.f) ? e : -1.0e10f;
      ex[nt][r] = e;
      mx = fmaxf(mx, e);
    }
    mx = fmaxf(mx, __shfl_xor(mx, 1));
    mx = fmaxf(mx, __shfl_xor(mx, 2));
    mx = fmaxf(mx, __shfl_xor(mx, 4));
    mx = fmaxf(mx, __shfl_xor(mx, 8));
    float s_ = 0.f;
#pragma unroll
    for (int nt = 0; nt < 8; ++nt) {
      const float p = expf(ex[nt][r] - mx);
      ex[nt][r] = p;
      s_ += p;
    }
    s_ += __shfl_xor(s_, 1);
    s_ += __shfl_xor(s_, 2);
    s_ += __shfl_xor(s_, 4);
    s_ += __shfl_xor(s_, 8);
    rsum[r] = s_;
  }

  __syncthreads();
  char* Pb = Ks + wid * 4096;
#pragma unroll
  for (int r = 0; r < 4; ++r) {
    const int row = lh * 4 + r;
#pragma unroll
    for (int nt = 0; nt < 8; ++nt) {
      const int col = nt * 16 + lr;
      const int off = (row * 256 + col * 2) ^ ((row & 7) << 4);
      *(bf16_t*)(Pb + off) = (bf16_t)ex[nt][r];
    }
  }
  __syncthreads();

  bf16x8 pf[4];
#pragma unroll
  for (int s = 0; s < 4; ++s)
    pf[s] = *(const bf16x8*)(Pb + lr * 256 + ((s * 64 + lh * 16) ^ ((lr & 7) << 4)));
  f32x4 acc2[8] = {};
#pragma unroll
  for (int nt = 0; nt < 8; ++nt) {
#pragma unroll
    for (int s = 0; s < 4; ++s) {
      const int row = nt * 16 + lr;
      const int cb = (s * 64 + lh * 16) ^ ((row & 7) << 4);
      const bf16x8 vf = *(const bf16x8*)(Vs + row * 256 + cb);
      acc2[nt] = __builtin_amdgcn_mfma_f32_16x16x32_bf16(pf[s], vf, acc2[nt], 0, 0, 0);
    }
  }

  float rs[4];
#pragma unroll
  for (int r = 0; r < 4; ++r) rs[r] = 1.f / rsum[r];
  bf16_t* Xb = X + ((size_t)b * LQLEN + q0 + wid * 16) * HIDN + h * 128;
#pragma unroll
  for (int nt = 0; nt < 8; ++nt)
#pragma unroll
    for (int r = 0; r < 4; ++r)
      Xb[(size_t)(lh * 4 + r) * HIDN + nt * 16 + lr] = (bf16_t)(acc2[nt][r] * rs[r]);
}

// ---------------------------------------------------------------------------
extern "C" void kernel_launch(void* const* d_in, const int* in_sizes, int n_in,
                              void* d_out, int out_size, void* d_ws, size_t ws_size,
                              hipStream_t stream) {
  const float* query = (const float*)d_in[0];
  const float* key   = (const float*)d_in[1];
  const float* value = (const float*)d_in[2];
  const float* atten = (const float*)d_in[3];
  const int*   mask  = (const int*)d_in[4];
  const float* Wq  = (const float*)d_in[5];  const float* bq   = (const float*)d_in[6];
  const float* Wk  = (const float*)d_in[7];  const float* bk   = (const float*)d_in[8];
  const float* Wv  = (const float*)d_in[9];  const float* bv   = (const float*)d_in[10];
  const float* Wat = (const float*)d_in[11]; const float* batt = (const float*)d_in[12];
  const float* Wfc = (const float*)d_in[13]; const float* bfc  = (const float*)d_in[14];

  char* ws = (char*)d_ws;
  bf16_t* qbf = (bf16_t*)(ws + 0x0000000);   // 64MB  [B,LQ,HID] bf16
  bf16_t* abf = (bf16_t*)(ws + 0x4000000);   // 64MB
  bf16_t* Qh  = (bf16_t*)(ws + 0x8000000);   // 64MB  [B,H,LQ,HD]
  bf16_t* Ah  = (bf16_t*)(ws + 0xC000000);   // 64MB
  char* sm = ws + 0x10000000;
  bf16_t* kbf = (bf16_t*)(sm + 0x000000);
  bf16_t* vbf = (bf16_t*)(sm + 0x200000);
  bf16_t* wqb = (bf16_t*)(sm + 0x400000);
  bf16_t* wkb = (bf16_t*)(sm + 0x600000);
  bf16_t* wvb = (bf16_t*)(sm + 0x800000);
  bf16_t* wab = (bf16_t*)(sm + 0xA00000);
  bf16_t* wfb = (bf16_t*)(sm + 0xC00000);
  bf16_t* Kh  = (bf16_t*)(sm + 0xE00000);    // [B,H,LK,HD]
  bf16_t* Vt  = (bf16_t*)(sm + 0x1000000);   // [B,H,HD,LK]
  bf16_t* X   = qbf;  // attention output reuses qbf (dead after Q-proj)

  auto conv = [&](const float* src, bf16_t* dst, int n) {
    const int n4 = n >> 2;
    int g = (n4 + 255) >> 8; if (g > 2048) g = 2048;
    convk<<<dim3(g), dim3(256), 0, stream>>>(src, dst, n4);
  };
  conv(query, qbf, NBATCH * LQLEN * HIDN);
  conv(atten, abf, NBATCH * LQLEN * HIDN);
  conv(key,   kbf, NBATCH * LKLEN * HIDN);
  conv(value, vbf, NBATCH * LKLEN * HIDN);
  conv(Wq,  wqb, HIDN * HIDN);
  conv(Wk,  wkb, HIDN * HIDN);
  conv(Wv,  wvb, HIDN * HIDN);
  conv(Wat, wab, HIDN * HIDN);
  conv(Wfc, wfb, HIDN * HIDN);

  // K/V projections (M = B*LK = 1024) — m97-structure kernel
  gemm_bt<0, 128><<<dim3(8, 8), dim3(256), 0, stream>>>(kbf, wkb, bk, (void*)Kh);
  gemm_bt<1, 128><<<dim3(8, 8), dim3(256), 0, stream>>>(vbf, wvb, bv, (void*)Vt);

  // Q / atten projections (M = 32768) — phased kernel (512 blocks)
  gemm8p<0><<<dim3(512), dim3(512), 0, stream>>>(qbf, wqb, bq, (void*)Qh);
  gemm8p<0><<<dim3(512), dim3(512), 0, stream>>>(abf, wab, batt, (void*)Ah);

  // fused attention
  attn_kernel<<<dim3(LQLEN / 64, NBATCH * NHEAD), dim3(256), 0, stream>>>(
      Qh, Ah, Kh, Vt, mask, X);

  // final FC -> f32 out
  gemm8p<2><<<dim3(512), dim3(512), 0, stream>>>(X, wfb, bfc, d_out);
}

// Round 5
// 464.914 us; speedup vs baseline: 1.1093x; 1.0124x over previous
//
#include <hip/hip_runtime.h>
#include <hip/hip_bf16.h>
#include <stdint.h>

typedef __bf16 bf16_t;
typedef __bf16 bf16x8 __attribute__((ext_vector_type(8)));
typedef __bf16 bf16x4 __attribute__((ext_vector_type(4)));
typedef float f32x4 __attribute__((ext_vector_type(4)));

// Problem constants
#define HIDN 1024
#define NHEAD 8
#define HDIM 128
#define NBATCH 8
#define LQLEN 4096
#define LKLEN 128

__device__ __forceinline__ void gload_lds16(const void* g, void* l) {
  __builtin_amdgcn_global_load_lds(
      (const __attribute__((address_space(1))) unsigned int*)g,
      (__attribute__((address_space(3))) unsigned int*)l, 16, 0, 0);
}

// ---------------------------------------------------------------------------
// f32 -> bf16 convert (vectorized float4 -> bf16x4)
// ---------------------------------------------------------------------------
__global__ __launch_bounds__(256) void convk(const float* __restrict__ in,
                                             bf16_t* __restrict__ out, int n4) {
  int i = blockIdx.x * blockDim.x + threadIdx.x;
  const int stride = gridDim.x * blockDim.x;
  for (; i < n4; i += stride) {
    const float4 v = ((const float4*)in)[i];
    bf16x4 o;
    o[0] = (bf16_t)v.x; o[1] = (bf16_t)v.y; o[2] = (bf16_t)v.z; o[3] = (bf16_t)v.w;
    ((bf16x4*)out)[i] = o;
  }
}

// ---------------------------------------------------------------------------
// Phased big GEMM: C[32768,1024] = A[32768,1024] @ Bw[1024,1024]^T + bias
// BM=BN=256, BK=32. 512 threads = 8 waves (2M x 4N), wave-tile 128x64.
// Bank swizzle for 64B rows: logical (row, slot16) stored at
//   row*64 + (slot ^ ((row>>1)&3))*16.  With this, each 16-lane read group
//   covers all 8 16B windows exactly 2x (2-way = free, m136).  Applied
//   both-sides: linear LDS dest + inverse-swizzled global source + swizzled
//   ds_read offset.
// LDS ring-of-4 (4 x 32KB = 128KB): during tile t stage tile t+3 into slot
//   (t+3)&3 = (t-1)&3 (WAR-safe by construction). Boundary vmcnt(8) keeps
//   2 tiles in flight; vmcnt(4)/(0) only in the final drain.
// Per tile: ph0 {read B(4)+A m0-3(4), stage A(t+3), bar, lgkm0, 16 MFMA,
//   bar}; ph1 {read A m4-7(4), stage B(t+3), bar, lgkm0, 16 MFMA};
//   boundary {vmcnt(N), bar}.  T5 setprio around MFMA clusters.
// MODE 0: bf16 head-layout store [B, H, 4096, 128];  MODE 2: f32 row-major.
// ---------------------------------------------------------------------------
template <int MODE>
__global__ __launch_bounds__(512, 2) void gemm8p(const bf16_t* __restrict__ A,
                                                 const bf16_t* __restrict__ Bw,
                                                 const float* __restrict__ bias,
                                                 void* __restrict__ Cout) {
  constexpr int NT = 32;       // K / 32
  constexpr int SLOT = 32768;  // A 16KB + B 16KB
  __shared__ uint4 smem_raw[8192];  // 128KB
  char* smem = (char*)smem_raw;

  const int tid = threadIdx.x;
  const int wid = tid >> 6, lane = tid & 63;
  const int lr = lane & 15, lh = lane >> 4;
  const int wr = wid >> 2, wc = wid & 3;  // wave grid 2 (M) x 4 (N)

  // XCD patch mapping (512 blocks, bijective; n fastest within XCD)
  const int bid = blockIdx.x;
  const int m_blk = (bid & 7) * 16 + (bid >> 5);
  const int n_blk = (bid >> 3) & 3;
  const int m0 = m_blk * 256, n0 = n_blk * 256;

  // ---- staging map: chunk c -> LDS row c>>2, LDS slot c&3 (linear dest).
  // Global source slot is inverse-swizzled: (c&3) ^ ((row>>1)&3), row>>1 = c>>3.
  const int c0 = tid, c1 = tid + 512;
  const int sc0 = (((c0 & 3) ^ ((c0 >> 3) & 3)) << 4);
  const int sc1 = (((c1 & 3) ^ ((c1 >> 3) & 3)) << 4);
  const char* srcA0 = (const char*)A + (size_t)(m0 + (c0 >> 2)) * 2048 + sc0;
  const char* srcA1 = (const char*)A + (size_t)(m0 + (c1 >> 2)) * 2048 + sc1;
  const char* srcB0 = (const char*)Bw + (size_t)(n0 + (c0 >> 2)) * 2048 + sc0;
  const char* srcB1 = (const char*)Bw + (size_t)(n0 + (c1 >> 2)) * 2048 + sc1;
  const int d0 = c0 * 16, d1 = c1 * 16;

  f32x4 acc[8][4] = {};

  // ---- prologue: stage tiles 0,1,2; wait tile 0 (8 outstanding = t1,t2)
#pragma unroll
  for (int tt = 0; tt < 3; ++tt) {
    char* dst = smem + tt * SLOT;
    gload_lds16(srcA0 + tt * 64, dst + d0);
    gload_lds16(srcA1 + tt * 64, dst + d1);
    gload_lds16(srcB0 + tt * 64, dst + 16384 + d0);
    gload_lds16(srcB1 + tt * 64, dst + 16384 + d1);
  }
  asm volatile("s_waitcnt vmcnt(8)" ::: "memory");
  __builtin_amdgcn_s_barrier();

  // ---- read-side: fragment row R = base16 + lr -> (R>>1)&3 = (lr>>1)&3
  const int swz = ((lr >> 1) & 3) << 4;
  const int aoff = (wr * 128 + lr) * 64 + ((lh << 4) ^ swz);
  const int boff = 16384 + (wc * 64 + lr) * 64 + ((lh << 4) ^ swz);

  for (int t = 0; t < NT; ++t) {
    const char* sA = smem + (t & 3) * SLOT + aoff;
    const char* sB = smem + (t & 3) * SLOT + boff;
    char* dst = smem + ((t + 3) & 3) * SLOT;
    const int kb = (t + 3) * 64;
    const bool pf = (t <= NT - 4);

    // ===== phase 0: read B(n0-3) + A(m0-3); stage A(t+3) ===================
    bf16x8 bfr[4], af0[4];
#pragma unroll
    for (int n = 0; n < 4; ++n) bfr[n] = *(const bf16x8*)(sB + n * 1024);
#pragma unroll
    for (int m = 0; m < 4; ++m) af0[m] = *(const bf16x8*)(sA + m * 1024);
    if (pf) {
      gload_lds16(srcA0 + kb, dst + d0);
      gload_lds16(srcA1 + kb, dst + d1);
    }
    __builtin_amdgcn_s_barrier();
    asm volatile("s_waitcnt lgkmcnt(0)" ::: "memory");
    __builtin_amdgcn_sched_barrier(0);
    __builtin_amdgcn_s_setprio(1);
#pragma unroll
    for (int m = 0; m < 4; ++m)
#pragma unroll
      for (int n = 0; n < 4; ++n)
        acc[m][n] = __builtin_amdgcn_mfma_f32_16x16x32_bf16(af0[m], bfr[n], acc[m][n], 0, 0, 0);
    __builtin_amdgcn_s_setprio(0);
    __builtin_amdgcn_s_barrier();

    // ===== phase 1: read A(m4-7); stage B(t+3) =============================
    bf16x8 af1[4];
#pragma unroll
    for (int m = 0; m < 4; ++m) af1[m] = *(const bf16x8*)(sA + (m + 4) * 1024);
    if (pf) {
      gload_lds16(srcB0 + kb, dst + 16384 + d0);
      gload_lds16(srcB1 + kb, dst + 16384 + d1);
    }
    __builtin_amdgcn_s_barrier();
    asm volatile("s_waitcnt lgkmcnt(0)" ::: "memory");
    __builtin_amdgcn_sched_barrier(0);
    __builtin_amdgcn_s_setprio(1);
#pragma unroll
    for (int m = 0; m < 4; ++m)
#pragma unroll
      for (int n = 0; n < 4; ++n)
        acc[m + 4][n] = __builtin_amdgcn_mfma_f32_16x16x32_bf16(af1[m], bfr[n], acc[m + 4][n], 0, 0, 0);
    __builtin_amdgcn_s_setprio(0);

    // ===== tile boundary: counted vmcnt (8 = 2 tiles in flight) ============
    if (t < NT - 1) {
      __builtin_amdgcn_sched_barrier(0);
      if (t <= NT - 4)
        asm volatile("s_waitcnt vmcnt(8)" ::: "memory");
      else if (t == NT - 3)
        asm volatile("s_waitcnt vmcnt(4)" ::: "memory");
      else
        asm volatile("s_waitcnt vmcnt(0)" ::: "memory");
      __builtin_amdgcn_sched_barrier(0);
      __builtin_amdgcn_s_barrier();
    }
  }

  // ---- epilogue. C/D layout: col = lane&15, row = (lane>>4)*4 + reg.
  if constexpr (MODE == 2) {
    float* C = (float*)Cout;
#pragma unroll
    for (int f = 0; f < 8; ++f) {
      const int gm = m0 + wr * 128 + f * 16 + lh * 4;
#pragma unroll
      for (int j = 0; j < 4; ++j) {
        const int gn = n0 + wc * 64 + j * 16 + lr;
        const float bb = bias[gn];
#pragma unroll
        for (int r = 0; r < 4; ++r)
          C[(size_t)(gm + r) * HIDN + gn] = acc[f][j][r] + bb;
      }
    }
  } else {
    bf16_t* C = (bf16_t*)Cout;
#pragma unroll
    for (int f = 0; f < 8; ++f) {
      const int gm = m0 + wr * 128 + f * 16 + lh * 4;
#pragma unroll
      for (int j = 0; j < 4; ++j) {
        const int gn = n0 + wc * 64 + j * 16 + lr;
        const float bb = bias[gn];
        const int h = gn >> 7, d = gn & 127;
#pragma unroll
        for (int r = 0; r < 4; ++r) {
          const int b = (gm + r) >> 12, l = (gm + r) & 4095;
          C[(((size_t)(b * NHEAD + h) * LQLEN + l) << 7) + d] = (bf16_t)(acc[f][j][r] + bb);
        }
      }
    }
  }
}

// ---------------------------------------------------------------------------
// Small GEMM (m97 structure) for the K/V projections (M = 1024 only)
// MODE 0: bf16 head-layout store  [B, H, LROW, 128]   (Kh)
// MODE 1: bf16 transposed head    [B, H, 128, LROW]   (Vt; LROW==128)
// ---------------------------------------------------------------------------
template <int MODE, int LROW>
__global__ __launch_bounds__(256) void gemm_bt(const bf16_t* __restrict__ A,
                                               const bf16_t* __restrict__ Bw,
                                               const float* __restrict__ bias,
                                               void* __restrict__ Cout) {
  constexpr int BK = 32;
  __shared__ uint4 AsRaw[128 * BK * 2 / 16];
  __shared__ uint4 BsRaw[128 * BK * 2 / 16];
  bf16_t* As = (bf16_t*)AsRaw;
  bf16_t* Bs = (bf16_t*)BsRaw;

  const int tid = threadIdx.x;
  const int wid = tid >> 6;
  const int lane = tid & 63;
  const int lr = lane & 15, lh = lane >> 4;
  const int m0 = blockIdx.x * 128, n0 = blockIdx.y * 128;
  const int wm = (wid >> 1) * 64, wn = (wid & 1) * 64;

  f32x4 acc[4][4] = {};

  const int srow = lane >> 2;
  const int scol = (lane & 3) * 16;

  for (int k0 = 0; k0 < HIDN; k0 += BK) {
#pragma unroll
    for (int i = 0; i < 2; ++i) {
      const int c = wid + i * 4;
      const int row = c * 16 + srow;
      gload_lds16((const char*)A + ((size_t)(m0 + row) * HIDN + k0) * 2 + scol,
                  (char*)As + c * 1024);
      gload_lds16((const char*)Bw + ((size_t)(n0 + row) * HIDN + k0) * 2 + scol,
                  (char*)Bs + c * 1024);
    }
    __syncthreads();

    bf16x8 af[4], bfr[4];
#pragma unroll
    for (int i = 0; i < 4; ++i) {
      af[i]  = *(const bf16x8*)(As + (wm + i * 16 + lr) * BK + lh * 8);
      bfr[i] = *(const bf16x8*)(Bs + (wn + i * 16 + lr) * BK + lh * 8);
    }
#pragma unroll
    for (int i = 0; i < 4; ++i)
#pragma unroll
      for (int j = 0; j < 4; ++j)
        acc[i][j] = __builtin_amdgcn_mfma_f32_16x16x32_bf16(af[i], bfr[j], acc[i][j], 0, 0, 0);
    __syncthreads();
  }

#pragma unroll
  for (int i = 0; i < 4; ++i) {
#pragma unroll
    for (int r = 0; r < 4; ++r) {
      const int gm = m0 + wm + i * 16 + lh * 4 + r;
#pragma unroll
      for (int j = 0; j < 4; ++j) {
        const int gn = n0 + wn + j * 16 + lr;
        const float v = acc[i][j][r] + bias[gn];
        const int b = gm / LROW, l = gm - b * LROW;
        const int h = gn >> 7, d = gn & 127;
        size_t idx;
        if constexpr (MODE == 0)
          idx = (((size_t)(b * NHEAD + h) * LROW + l) << 7) + d;
        else
          idx = (((size_t)(b * NHEAD + h) * 128 + d) << 7) + l;
        ((bf16_t*)Cout)[idx] = (bf16_t)v;
      }
    }
  }
}

// ---------------------------------------------------------------------------
// Fused attention: energy = QK^T/sqrt(128) + Ah, mask, softmax, x = P V
// ---------------------------------------------------------------------------
__global__ __launch_bounds__(256) void attn_kernel(
    const bf16_t* __restrict__ Qh, const bf16_t* __restrict__ Ah,
    const bf16_t* __restrict__ Kh, const bf16_t* __restrict__ Vt,
    const int* __restrict__ mask, bf16_t* __restrict__ X) {
  __shared__ uint4 KsRaw[2048];
  __shared__ uint4 VsRaw[2048];
  __shared__ float Ms[128];
  char* Ks = (char*)KsRaw;
  char* Vs = (char*)VsRaw;

  const int tid = threadIdx.x, wid = tid >> 6, lane = tid & 63;
  const int lr = lane & 15, lh = lane >> 4;
  const int bh = blockIdx.y, b = bh >> 3, h = bh & 7;
  const int q0 = blockIdx.x * 64;

  {
    const char* Kg = (const char*)(Kh + (size_t)bh * 16384);
    const char* Vg = (const char*)(Vt + (size_t)bh * 16384);
#pragma unroll
    for (int it = 0; it < 8; ++it) {
      const int e = it * 256 + tid;
      const int row = e >> 4;
      const int cb = (e & 15) << 4;
      const int dst = row * 256 + (cb ^ ((row & 7) << 4));
      *(uint4*)(Ks + dst) = *(const uint4*)(Kg + row * 256 + cb);
      *(uint4*)(Vs + dst) = *(const uint4*)(Vg + row * 256 + cb);
    }
  }
  if (tid < 128) Ms[tid] = (mask[b * 128 + tid] == 0) ? 0.f : 1.f;

  bf16x8 qf[4];
  {
    const bf16_t* Qb = Qh + ((size_t)bh * LQLEN + q0 + wid * 16 + lr) * 128;
#pragma unroll
    for (int s = 0; s < 4; ++s) qf[s] = *(const bf16x8*)(Qb + s * 32 + lh * 8);
  }
  __syncthreads();

  f32x4 acc[8] = {};
#pragma unroll
  for (int nt = 0; nt < 8; ++nt) {
#pragma unroll
    for (int s = 0; s < 4; ++s) {
      const int row = nt * 16 + lr;
      const int cb = (s * 64 + lh * 16) ^ ((row & 7) << 4);
      const bf16x8 kf = *(const bf16x8*)(Ks + row * 256 + cb);
      acc[nt] = __builtin_amdgcn_mfma_f32_16x16x32_bf16(qf[s], kf, acc[nt], 0, 0, 0);
    }
  }

  float ex[8][4];
  float rsum[4];
  const float sc = 0.08838834764831845f;
  const bf16_t* Ab = Ah + ((size_t)bh * LQLEN + q0 + wid * 16) * 128;
#pragma unroll
  for (int r = 0; r < 4; ++r) {
    const int row = lh * 4 + r;
    float mx = -3.0e38f;
#pragma unroll
    for (int nt = 0; nt < 8; ++nt) {
      const int col = nt * 16 + lr;
      float e = acc[nt][r] * sc + (float)Ab[row * 128 + col];
      e = (Ms[col] != 0.f) ? e : -1.0e10f;
      ex[nt][r] = e;
      mx = fmaxf(mx, e);
    }
    mx = fmaxf(mx, __shfl_xor(mx, 1));
    mx = fmaxf(mx, __shfl_xor(mx, 2));
    mx = fmaxf(mx, __shfl_xor(mx, 4));
    mx = fmaxf(mx, __shfl_xor(mx, 8));
    float s_ = 0.f;
#pragma unroll
    for (int nt = 0; nt < 8; ++nt) {
      const float p = expf(ex[nt][r] - mx);
      ex[nt][r] = p;
      s_ += p;
    }
    s_ += __shfl_xor(s_, 1);
    s_ += __shfl_xor(s_, 2);
    s_ += __shfl_xor(s_, 4);
    s_ += __shfl_xor(s_, 8);
    rsum[r] = s_;
  }

  __syncthreads();
  char* Pb = Ks + wid * 4096;
#pragma unroll
  for (int r = 0; r < 4; ++r) {
    const int row = lh * 4 + r;
#pragma unroll
    for (int nt = 0; nt < 8; ++nt) {
      const int col = nt * 16 + lr;
      const int off = (row * 256 + col * 2) ^ ((row & 7) << 4);
      *(bf16_t*)(Pb + off) = (bf16_t)ex[nt][r];
    }
  }
  __syncthreads();

  bf16x8 pf[4];
#pragma unroll
  for (int s = 0; s < 4; ++s)
    pf[s] = *(const bf16x8*)(Pb + lr * 256 + ((s * 64 + lh * 16) ^ ((lr & 7) << 4)));
  f32x4 acc2[8] = {};
#pragma unroll
  for (int nt = 0; nt < 8; ++nt) {
#pragma unroll
    for (int s = 0; s < 4; ++s) {
      const int row = nt * 16 + lr;
      const int cb = (s * 64 + lh * 16) ^ ((row & 7) << 4);
      const bf16x8 vf = *(const bf16x8*)(Vs + row * 256 + cb);
      acc2[nt] = __builtin_amdgcn_mfma_f32_16x16x32_bf16(pf[s], vf, acc2[nt], 0, 0, 0);
    }
  }

  float rs[4];
#pragma unroll
  for (int r = 0; r < 4; ++r) rs[r] = 1.f / rsum[r];
  bf16_t* Xb = X + ((size_t)b * LQLEN + q0 + wid * 16) * HIDN + h * 128;
#pragma unroll
  for (int nt = 0; nt < 8; ++nt)
#pragma unroll
    for (int r = 0; r < 4; ++r)
      Xb[(size_t)(lh * 4 + r) * HIDN + nt * 16 + lr] = (bf16_t)(acc2[nt][r] * rs[r]);
}

// ---------------------------------------------------------------------------
extern "C" void kernel_launch(void* const* d_in, const int* in_sizes, int n_in,
                              void* d_out, int out_size, void* d_ws, size_t ws_size,
                              hipStream_t stream) {
  const float* query = (const float*)d_in[0];
  const float* key   = (const float*)d_in[1];
  const float* value = (const float*)d_in[2];
  const float* atten = (const float*)d_in[3];
  const int*   mask  = (const int*)d_in[4];
  const float* Wq  = (const float*)d_in[5];  const float* bq   = (const float*)d_in[6];
  const float* Wk  = (const float*)d_in[7];  const float* bk   = (const float*)d_in[8];
  const float* Wv  = (const float*)d_in[9];  const float* bv   = (const float*)d_in[10];
  const float* Wat = (const float*)d_in[11]; const float* batt = (const float*)d_in[12];
  const float* Wfc = (const float*)d_in[13]; const float* bfc  = (const float*)d_in[14];

  char* ws = (char*)d_ws;
  bf16_t* qbf = (bf16_t*)(ws + 0x0000000);   // 64MB  [B,LQ,HID] bf16
  bf16_t* abf = (bf16_t*)(ws + 0x4000000);   // 64MB
  bf16_t* Qh  = (bf16_t*)(ws + 0x8000000);   // 64MB  [B,H,LQ,HD]
  bf16_t* Ah  = (bf16_t*)(ws + 0xC000000);   // 64MB
  char* sm = ws + 0x10000000;
  bf16_t* kbf = (bf16_t*)(sm + 0x000000);
  bf16_t* vbf = (bf16_t*)(sm + 0x200000);
  bf16_t* wqb = (bf16_t*)(sm + 0x400000);
  bf16_t* wkb = (bf16_t*)(sm + 0x600000);
  bf16_t* wvb = (bf16_t*)(sm + 0x800000);
  bf16_t* wab = (bf16_t*)(sm + 0xA00000);
  bf16_t* wfb = (bf16_t*)(sm + 0xC00000);
  bf16_t* Kh  = (bf16_t*)(sm + 0xE00000);    // [B,H,LK,HD]
  bf16_t* Vt  = (bf16_t*)(sm + 0x1000000);   // [B,H,HD,LK]
  bf16_t* X   = qbf;  // attention output reuses qbf (dead after Q-proj)

  auto conv = [&](const float* src, bf16_t* dst, int n) {
    const int n4 = n >> 2;
    int g = (n4 + 255) >> 8; if (g > 2048) g = 2048;
    convk<<<dim3(g), dim3(256), 0, stream>>>(src, dst, n4);
  };
  conv(query, qbf, NBATCH * LQLEN * HIDN);
  conv(atten, abf, NBATCH * LQLEN * HIDN);
  conv(key,   kbf, NBATCH * LKLEN * HIDN);
  conv(value, vbf, NBATCH * LKLEN * HIDN);
  conv(Wq,  wqb, HIDN * HIDN);
  conv(Wk,  wkb, HIDN * HIDN);
  conv(Wv,  wvb, HIDN * HIDN);
  conv(Wat, wab, HIDN * HIDN);
  conv(Wfc, wfb, HIDN * HIDN);

  // K/V projections (M = B*LK = 1024) — m97-structure kernel
  gemm_bt<0, 128><<<dim3(8, 8), dim3(256), 0, stream>>>(kbf, wkb, bk, (void*)Kh);
  gemm_bt<1, 128><<<dim3(8, 8), dim3(256), 0, stream>>>(vbf, wvb, bv, (void*)Vt);

  // Q / atten projections (M = 32768) — phased kernel (512 blocks)
  gemm8p<0><<<dim3(512), dim3(512), 0, stream>>>(qbf, wqb, bq, (void*)Qh);
  gemm8p<0><<<dim3(512), dim3(512), 0, stream>>>(abf, wab, batt, (void*)Ah);

  // fused attention
  attn_kernel<<<dim3(LQLEN / 64, NBATCH * NHEAD), dim3(256), 0, stream>>>(
      Qh, Ah, Kh, Vt, mask, X);

  // final FC -> f32 out
  gemm8p<2><<<dim3(512), dim3(512), 0, stream>>>(X, wfb, bfc, d_out);
}